// Round 12
// baseline (194.302 us; speedup 1.0000x reference)
//
#include <hip/hip_runtime.h>
#include <hip/hip_bf16.h>
#include <cstdint>

#define B_ 4
#define T_ 2048
#define C_ 1024
#define H_ 16
#define D_ 64
#define NC_ 32   // chunks
#define L_ 64    // chunk length

typedef __attribute__((ext_vector_type(8))) short bf16x8;
typedef __attribute__((ext_vector_type(4))) float f32x4;

static __device__ __forceinline__ unsigned short f2bf(float f) {
  unsigned u = __float_as_uint(f);
  u += 0x7fff + ((u >> 16) & 1);   // round-to-nearest-even
  return (unsigned short)(u >> 16);
}
static __device__ __forceinline__ float bf2f(unsigned short b) {
  return __uint_as_float(((unsigned)b) << 16);
}
// XOR swizzle for 128B-stride LDS rows (T2): keeps 16B alignment, <=2-way conflicts
static __device__ __forceinline__ int swz128(int row, int byte) {
  return row * 128 + (byte ^ ((row & 7) << 4));
}

// Barrier that does NOT drain vmcnt (T4): LDS edges fenced via lgkmcnt(0).
#define LDS_BARRIER() asm volatile("s_waitcnt lgkmcnt(0)\ns_barrier" ::: "memory")

// ---------------- f32 -> bf16 convert (x + 4 weights in ONE launch) ----------------
__global__ __launch_bounds__(256) void cvt_all(const float* __restrict__ x,
                                               const float* __restrict__ wq,
                                               const float* __restrict__ wk,
                                               const float* __restrict__ wv,
                                               const float* __restrict__ wp,
                                               unsigned short* __restrict__ xbf,
                                               unsigned short* __restrict__ W3,
                                               unsigned short* __restrict__ Wp) {
  const int bidx = blockIdx.x;
  const float* src;
  unsigned short* dst;
  long base;
  if (bidx < 8192) {
    src = x; dst = xbf; base = (long)bidx * 1024;
  } else {
    const int g = (bidx - 8192) >> 10;
    src = (g == 0) ? wq : (g == 1) ? wk : (g == 2) ? wv : wp;
    dst = (g < 3) ? (W3 + (long)g * 1048576) : Wp;
    base = (long)((bidx - 8192) & 1023) * 1024;
  }
  long i = base + threadIdx.x * 4;
  float4 v = *reinterpret_cast<const float4*>(src + i);
  ushort4 o;
  o.x = f2bf(v.x); o.y = f2bf(v.y); o.z = f2bf(v.z); o.w = f2bf(v.w);
  *reinterpret_cast<ushort4*>(dst + i) = o;
}

// ================= 8-phase 256x256 bf16 GEMM (T1+T2+T3+T4+T5) ==========
#define STAGE256(GP, GR0, KT, LOFF) do {                                          \
    const unsigned short* _s = (GP) + ((GR0) + wid * 8 + lr8) * 1024L             \
                               + (long)(KT) * 64 + skb * 8;                       \
    char* _d = (char*)lds + (LOFF) + wid * 1024;                                  \
    __builtin_amdgcn_global_load_lds((const __attribute__((address_space(1))) void*)_s,      \
        (__attribute__((address_space(3))) void*)_d, 16, 0, 0);                   \
    __builtin_amdgcn_global_load_lds((const __attribute__((address_space(1))) void*)(_s + 64 * 1024L), \
        (__attribute__((address_space(3))) void*)(_d + 8192), 16, 0, 0);          \
  } while (0)

#define PHASE256(AO, BO, MH, NH, STG) do {                                        \
    asm volatile("s_waitcnt vmcnt(6)" ::: "memory");                              \
    bf16x8 av[4][2], bv[2][2];                                                    \
    {                                                                             \
      const char* ab = (const char*)lds + (AO) + (MH) * 16384 + arow;             \
      const char* bb = (const char*)lds + (BO) + (NH) * 16384 + brow;             \
      _Pragma("unroll")                                                           \
      for (int j = 0; j < 4; ++j) {                                               \
        av[j][0] = *(const bf16x8*)(ab + j * 4096 + cb0);                         \
        av[j][1] = *(const bf16x8*)(ab + j * 4096 + cb1);                         \
      }                                                                           \
      _Pragma("unroll")                                                           \
      for (int j2 = 0; j2 < 2; ++j2) {                                            \
        bv[j2][0] = *(const bf16x8*)(bb + j2 * 8192 + cb0);                       \
        bv[j2][1] = *(const bf16x8*)(bb + j2 * 8192 + cb1);                       \
      }                                                                           \
    }                                                                             \
    STG;                                                                          \
    __builtin_amdgcn_s_barrier();                                                 \
    asm volatile("s_waitcnt lgkmcnt(0)" ::: "memory");                            \
    __builtin_amdgcn_sched_barrier(0);                                            \
    __builtin_amdgcn_s_setprio(1);                                                \
    _Pragma("unroll")                                                             \
    for (int j = 0; j < 4; ++j)                                                   \
      _Pragma("unroll")                                                           \
      for (int j2 = 0; j2 < 2; ++j2)                                              \
        acc[(MH) * 4 + j][(NH) * 2 + j2] = __builtin_amdgcn_mfma_f32_16x16x32_bf16( \
            av[j][0], bv[j2][0], acc[(MH) * 4 + j][(NH) * 2 + j2], 0, 0, 0);      \
    _Pragma("unroll")                                                             \
    for (int j = 0; j < 4; ++j)                                                   \
      _Pragma("unroll")                                                           \
      for (int j2 = 0; j2 < 2; ++j2)                                              \
        acc[(MH) * 4 + j][(NH) * 2 + j2] = __builtin_amdgcn_mfma_f32_16x16x32_bf16( \
            av[j][1], bv[j2][1], acc[(MH) * 4 + j][(NH) * 2 + j2], 0, 0, 0);      \
    __builtin_amdgcn_s_setprio(0);                                                \
    __builtin_amdgcn_s_barrier();                                                 \
  } while (0)

__global__ __launch_bounds__(512, 2) void gemm256_bt(
    const unsigned short* __restrict__ A,
    const unsigned short* __restrict__ Bw,
    unsigned short* __restrict__ C, int N) {
  __shared__ __align__(16) char lds[131072];
  enum { EA = 0, EB = 32768, OA = 65536, OB = 98304, HF = 16384 };
  const int tid = threadIdx.x;
  const int wid = tid >> 6, lane = tid & 63;
  const int wm = wid >> 2, wn = wid & 3;
  const int f = lane & 15, g = lane >> 4;
  const int lr8 = lane >> 3, lc = lane & 7;
  const int skb = lc ^ lr8;
  // T1: bijective XCD-chunked swizzle (nwg % 8 == 0)
  const int bid = blockIdx.y * gridDim.x + blockIdx.x;
  const int cpx = (gridDim.x * gridDim.y) >> 3;
  const int sw = (bid & 7) * cpx + (bid >> 3);
  const long bM = (long)(sw / gridDim.x) * 256;
  const long bN = (long)(sw % gridDim.x) * 256;
  const int cb0 = ((0 + g) ^ (f & 7)) * 16;
  const int cb1 = ((4 + g) ^ (f & 7)) * 16;
  const int arow = (wm * 16 + f) * 128;
  const int brow = (wn * 16 + f) * 128;

  f32x4 acc[8][4] = {};

  STAGE256(A, bM, 0, EA);
  STAGE256(Bw, bN, 0, EB);
  STAGE256(A, bM + 128, 0, EA + HF);
  STAGE256(Bw, bN + 128, 0, EB + HF);
  STAGE256(Bw, bN, 1, OB);
  STAGE256(A, bM, 1, OA);
  asm volatile("s_waitcnt vmcnt(8)" ::: "memory");
  __builtin_amdgcn_s_barrier();

  for (int i = 0; i < 8; ++i) {
    const int todd = 2 * i + 1;
    int te = 2 * i + 2; if (te > 14) te = 14;
    int to = 2 * i + 3; if (to > 15) to = 15;
    PHASE256(EA, EB, 0, 0, STAGE256(A, bM + 128, todd, OA + HF));
    PHASE256(EA, EB, 1, 0, STAGE256(Bw, bN + 128, todd, OB + HF));
    PHASE256(EA, EB, 0, 1, STAGE256(Bw, bN, te, EB));
    PHASE256(EA, EB, 1, 1, STAGE256(A, bM, te, EA));
    PHASE256(OA, OB, 0, 0, STAGE256(A, bM + 128, te, EA + HF));
    PHASE256(OA, OB, 1, 0, STAGE256(Bw, bN + 128, te, EB + HF));
    PHASE256(OA, OB, 0, 1, STAGE256(Bw, bN, to, OB));
    PHASE256(OA, OB, 1, 1, STAGE256(A, bM, to, OA));
  }

#pragma unroll
  for (int mf = 0; mf < 8; ++mf) {
    long row = bM + (mf >> 2) * 128 + (mf & 3) * 32 + wm * 16 + g * 4;
#pragma unroll
    for (int nf = 0; nf < 4; ++nf) {
      long col = bN + (nf >> 1) * 128 + (nf & 1) * 64 + wn * 16 + f;
#pragma unroll
      for (int r = 0; r < 4; ++r)
        C[(row + r) * (long)N + col] = f2bf(acc[mf][nf][r]);
    }
  }
}

// ---------------- m97-style 128x128 GEMM (gemm2) ----------------
template<int OUT_BF16>
__global__ __launch_bounds__(256) void gemm_bt(const unsigned short* __restrict__ A,
                                               const unsigned short* __restrict__ Bw,
                                               void* __restrict__ Cp,
                                               int M, int N, int K) {
  __shared__ __align__(16) unsigned short sA[128 * 32];
  __shared__ __align__(16) unsigned short sB[128 * 32];
  const int tid = threadIdx.x;
  const int wid = tid >> 6, lane = tid & 63;
  const int wm = wid >> 1, wn = wid & 1;
  const int bid = blockIdx.y * gridDim.x + blockIdx.x;
  const int cpx = (gridDim.x * gridDim.y) >> 3;
  const int sw = (bid & 7) * cpx + (bid >> 3);
  const long blockM = (long)(sw / gridDim.x) * 128;
  const long blockN = (long)(sw % gridDim.x) * 128;

  f32x4 acc[4][4] = {};

  const int ar = lane >> 2;
  const int ac = (lane & 3) * 8;
  const unsigned short* Abase = A + (blockM + wid * 32 + ar) * (long)K + ac;
  const unsigned short* Bbase = Bw + (blockN + wid * 32 + ar) * (long)K + ac;
  char* sAb = (char*)sA + wid * 2048;
  char* sBb = (char*)sB + wid * 2048;

  for (int k0 = 0; k0 < K; k0 += 32) {
    __syncthreads();
    __builtin_amdgcn_global_load_lds((const __attribute__((address_space(1))) void*)(Abase + k0),
                                     (__attribute__((address_space(3))) void*)(sAb), 16, 0, 0);
    __builtin_amdgcn_global_load_lds((const __attribute__((address_space(1))) void*)(Abase + 16 * (long)K + k0),
                                     (__attribute__((address_space(3))) void*)(sAb + 1024), 16, 0, 0);
    __builtin_amdgcn_global_load_lds((const __attribute__((address_space(1))) void*)(Bbase + k0),
                                     (__attribute__((address_space(3))) void*)(sBb), 16, 0, 0);
    __builtin_amdgcn_global_load_lds((const __attribute__((address_space(1))) void*)(Bbase + 16 * (long)K + k0),
                                     (__attribute__((address_space(3))) void*)(sBb + 1024), 16, 0, 0);
    __syncthreads();

    const int koff = (lane >> 4) * 8;
    const int rA = wm * 64 + (lane & 15);
    const int rB = wn * 64 + (lane & 15);
    bf16x8 af[4], bfr[4];
#pragma unroll
    for (int m = 0; m < 4; ++m)
      af[m] = *reinterpret_cast<const bf16x8*>(&sA[(rA + m * 16) * 32 + koff]);
#pragma unroll
    for (int n = 0; n < 4; ++n)
      bfr[n] = *reinterpret_cast<const bf16x8*>(&sB[(rB + n * 16) * 32 + koff]);
#pragma unroll
    for (int m = 0; m < 4; ++m)
#pragma unroll
      for (int n = 0; n < 4; ++n)
        acc[m][n] = __builtin_amdgcn_mfma_f32_16x16x32_bf16(af[m], bfr[n], acc[m][n], 0, 0, 0);
  }

  const int cr = (lane >> 4) * 4;
  const int cc = lane & 15;
#pragma unroll
  for (int m = 0; m < 4; ++m) {
    long R = blockM + wm * 64 + m * 16 + cr;
#pragma unroll
    for (int n = 0; n < 4; ++n) {
      long Cc = blockN + wn * 64 + n * 16 + cc;
#pragma unroll
      for (int r = 0; r < 4; ++r) {
        if (OUT_BF16)
          ((unsigned short*)Cp)[(R + r) * (long)N + Cc] = f2bf(acc[m][n][r]);
        else
          ((float*)Cp)[(R + r) * (long)N + Cc] = acc[m][n][r];
      }
    }
  }
}

// ---------------- phase 1: per (bh, chunk) WY precompute ----------------
// Packs KT = K_norm^T into the dead V-slot of qkv (scan stages it vectorized).
__global__ __launch_bounds__(256) void chunk_prep(
    unsigned short* __restrict__ qkv,
    const float* __restrict__ a_raw, const float* __restrict__ b_raw,
    unsigned short* __restrict__ Ubuf, unsigned short* __restrict__ Wbuf,
    unsigned short* __restrict__ SLbuf) {
  __shared__ __align__(16) unsigned short sK[64 * 64];
  __shared__ __align__(16) unsigned short sQ[64 * 64];
  __shared__ __align__(16) unsigned short sV[64 * 64];
  __shared__ float sA[64 * 64];

  const int blk = blockIdx.x;           // bh*32 + c
  const int bh = blk >> 5, c = blk & 31;
  const int b = bh >> 4, h = bh & 15;
  const int tid = threadIdx.x;
  const int wid = tid >> 6, lane = tid & 63;

  const float alpha = 0.5f / (1.f + __expf(-a_raw[h]));
  const float beta  = 0.5f / (1.f + __expf(-b_raw[h]));

  {
    const int row = tid >> 2, cg = tid & 3;
    unsigned short* gp = qkv + (long)(b * 2048 + c * 64 + row) * 3072 + h * 64 + cg * 16;
    bf16x8 q0 = *(const bf16x8*)(gp);
    bf16x8 q1 = *(const bf16x8*)(gp + 8);
    bf16x8 k0 = *(const bf16x8*)(gp + 1024);
    bf16x8 k1 = *(const bf16x8*)(gp + 1024 + 8);
    bf16x8 v0 = *(const bf16x8*)(gp + 2048);
    bf16x8 v1 = *(const bf16x8*)(gp + 2048 + 8);
    float kf[16];
    float ss = 0.f;
#pragma unroll
    for (int i = 0; i < 8; ++i) { kf[i] = bf2f((unsigned short)k0[i]); ss += kf[i] * kf[i]; }
#pragma unroll
    for (int i = 0; i < 8; ++i) { kf[8 + i] = bf2f((unsigned short)k1[i]); ss += kf[8 + i] * kf[8 + i]; }
    ss += __shfl_xor(ss, 1);
    ss += __shfl_xor(ss, 2);
    const float inv = 1.f / fmaxf(sqrtf(ss), 1e-12f);
    bf16x8 n0, n1;
#pragma unroll
    for (int i = 0; i < 8; ++i) { n0[i] = (short)f2bf(kf[i] * inv); n1[i] = (short)f2bf(kf[8 + i] * inv); }
    *(bf16x8*)((char*)sK + swz128(row, cg * 32)) = n0;
    *(bf16x8*)((char*)sK + swz128(row, cg * 32 + 16)) = n1;
    *(bf16x8*)((char*)sQ + swz128(row, cg * 32)) = q0;
    *(bf16x8*)((char*)sQ + swz128(row, cg * 32 + 16)) = q1;
    *(bf16x8*)((char*)sV + row * 128 + cg * 32) = v0;
    *(bf16x8*)((char*)sV + row * 128 + cg * 32 + 16) = v1;
  }
  __syncthreads();

  // KT pack: slot[e][t] = K_norm[t][e] -> qkv V-slot (coalesced bf16x8 stores)
  {
    const int erow = tid >> 2, tq = tid & 3;
    unsigned short kt[16];
#pragma unroll
    for (int i = 0; i < 16; ++i)
      kt[i] = *(const unsigned short*)((const char*)sK + swz128(tq * 16 + i, 2 * erow));
    unsigned short* vp = qkv + (long)(b * 2048 + c * 64 + erow) * 3072 + 2048 + h * 64 + tq * 16;
    *(bf16x8*)vp = *(const bf16x8*)kt;
    *(bf16x8*)(vp + 8) = *(const bf16x8*)(kt + 8);
  }

  const int rfrag = lane & 15, koff = (lane >> 4) * 8, crow = (lane >> 4) * 4;
  const int w2 = wid & 1;
  if (wid < 2) {
#pragma unroll
    for (int mt = 0; mt < 2; ++mt) {
      const int m = w2 * 2 + mt;
      const int ra = 16 * m + rfrag;
      f32x4 acc[4] = {};
#pragma unroll
      for (int ks = 0; ks < 2; ++ks) {
        bf16x8 af = *(const bf16x8*)((const char*)sK + swz128(ra, ks * 64 + koff * 2));
#pragma unroll
        for (int n = 0; n < 4; ++n) {
          bf16x8 bf = *(const bf16x8*)((const char*)sK + swz128(16 * n + rfrag, ks * 64 + koff * 2));
          acc[n] = __builtin_amdgcn_mfma_f32_16x16x32_bf16(af, bf, acc[n], 0, 0, 0);
        }
      }
#pragma unroll
      for (int n = 0; n < 4; ++n)
#pragma unroll
        for (int r = 0; r < 4; ++r)
          sA[(16 * m + crow + r) * 64 + 16 * n + rfrag] = acc[n][r];
    }
  } else {
#pragma unroll
    for (int mt = 0; mt < 2; ++mt) {
      const int m = w2 * 2 + mt;
      const int ra = 16 * m + rfrag;
      f32x4 acc[4] = {};
#pragma unroll
      for (int ks = 0; ks < 2; ++ks) {
        bf16x8 af = *(const bf16x8*)((const char*)sQ + swz128(ra, ks * 64 + koff * 2));
#pragma unroll
        for (int n = 0; n < 4; ++n) {
          bf16x8 bf = *(const bf16x8*)((const char*)sK + swz128(16 * n + rfrag, ks * 64 + koff * 2));
          acc[n] = __builtin_amdgcn_mfma_f32_16x16x32_bf16(af, bf, acc[n], 0, 0, 0);
        }
      }
#pragma unroll
      for (int n = 0; n < 4; ++n)
#pragma unroll
        for (int r = 0; r < 4; ++r) {
          int t = 16 * m + crow + r, j = 16 * n + rfrag;
          SLbuf[(long)blk * 4096 + t * 64 + j] = (j < t) ? f2bf(acc[n][r]) : (unsigned short)0;
        }
    }
  }
  __syncthreads();

  if (wid < 2) {
    const int d = lane;
    float x[64];
#pragma unroll
    for (int t = 0; t < 64; ++t) {
      float rhs;
      if (wid == 0) rhs = beta * bf2f(sV[t * 64 + d]);
      else          rhs = alpha * bf2f(*(const unsigned short*)((const char*)sK + swz128(t, 2 * d)));
      float s = 0.f;
#pragma unroll
      for (int j = 0; j < t; ++j) s = fmaf(sA[t * 64 + j], x[j], s);
      x[t] = rhs - alpha * s;
    }
    unsigned short* ob = (wid == 0 ? Ubuf : Wbuf) + (long)blk * 4096 + d;
#pragma unroll
    for (int t = 0; t < 64; ++t) ob[t * 64] = f2bf(x[t]);
  }
}

// ---------------- phase 2: fused 4-quarter chunk recurrence ----------------
// Block = one (b,h): 1024 threads = 16 waves = 4 dq-groups x 4 t-tile waves.
// Shared Q/W/SL/KT staged ONCE per block (2-3 b128 writes/thread, dbuf);
// per-dq U/GT/sS private. 4 waves/SIMD -> ds_read latency cross-hidden.
// Per-wave compute identical to R11 (8 MFMA/chunk). 2 barriers/chunk.
__global__ __launch_bounds__(1024) void chunk_scan(
    const unsigned short* __restrict__ qkv,
    const unsigned short* __restrict__ Ubuf, const unsigned short* __restrict__ Wbuf,
    const unsigned short* __restrict__ SLbuf,
    const float* __restrict__ state_in, unsigned short* __restrict__ ybuf,
    float* __restrict__ state_out) {
  // bytes: shared buf k at k*32768 {Q+0, W+8192, SL+16384, KT+24576};
  // U dbuf: 65536 + dq*4096 + k*2048; GT: 81920 + dq*2048; sS: 90112 + dq*2048
  __shared__ __align__(16) char lds[98304];

  const int bid0 = blockIdx.x;
  const int bh = (bid0 & 7) * 8 + (bid0 >> 3);   // T1 (64 % 8 == 0)
  const int b = bh >> 4, h = bh & 15;
  const int tid = threadIdx.x;
  const int wid = tid >> 6, lane = tid & 63;
  const int dq = wid >> 2, w4 = wid & 3;          // dq group, t-tile wave
  const int rfrag = lane & 15, koff = (lane >> 4) * 8, crow = (lane >> 4) * 4;

  // shared-tile staging role: tile = tid>>8 (Q,W,SL,KT), row, col-group
  const int stile = tid >> 8, srow = (tid >> 2) & 63, scg = tid & 3;
  // per-group U staging role
  const int tg = tid & 255, ur = tg >> 1, uh = tg & 1;

  char* gt  = lds + 81920 + dq * 2048;
  char* ssb = lds + 90112 + dq * 2048;

  const unsigned short* gsrc0;
  long gstride;
  if (stile == 0)      { gsrc0 = qkv + (long)(b * 2048 + srow) * 3072 + h * 64 + scg * 16; gstride = 64 * 3072; }
  else if (stile == 1) { gsrc0 = Wbuf + ((long)(bh * 32) * 64 + srow) * 64 + scg * 16; gstride = 4096; }
  else if (stile == 2) { gsrc0 = SLbuf + ((long)(bh * 32) * 64 + srow) * 64 + scg * 16; gstride = 4096; }
  else                 { gsrc0 = qkv + (long)(b * 2048 + srow) * 3072 + 2048 + h * 64 + scg * 16; gstride = 64 * 3072; }
  const unsigned short* usrc0 = Ubuf + ((long)(bh * 32) * 64 + ur) * 64 + dq * 16 + uh * 8;

  bf16x8 rv0 = {}, rv1 = {}, uv = {};
#define LOADREGS(CN) do {                                                       \
    const unsigned short* gp = gsrc0 + (long)(CN) * gstride;                    \
    rv0 = *(const bf16x8*)gp;                                                   \
    rv1 = *(const bf16x8*)(gp + 8);                                             \
    if (tg < 128) uv = *(const bf16x8*)(usrc0 + (long)(CN) * 4096);             \
  } while (0)

#define WRITE_TILES(BUF) do {                                                   \
    char* bp_ = lds + (BUF) * 32768 + stile * 8192;                             \
    *(bf16x8*)(bp_ + swz128(srow, scg * 32)) = rv0;                             \
    *(bf16x8*)(bp_ + swz128(srow, scg * 32 + 16)) = rv1;                        \
    if (tg < 128)                                                               \
      *(bf16x8*)(lds + 65536 + dq * 4096 + (BUF) * 2048 + (ur * 16 + uh * 8) * 2) = uv; \
  } while (0)

  f32x4 sacc;
#pragma unroll
  for (int r = 0; r < 4; ++r)
    sacc[r] = state_in[(long)bh * 4096 + (dq * 16 + crow + r) * 64 + 16 * w4 + rfrag];
#pragma unroll
  for (int r = 0; r < 4; ++r)
    *(unsigned short*)(ssb + swz128(crow + r, 2 * (16 * w4 + rfrag))) = f2bf(sacc[r]);

  // prologue
  LOADREGS(0);
  WRITE_TILES(0);
  LOADREGS(1);
  LDS_BARRIER();

  for (int c = 0; c < NC_; ++c) {
    const int cur = c & 1;
    const char* bp = lds + cur * 32768;
    const char* up = lds + 65536 + dq * 4096 + cur * 2048;
    const int ta = 16 * w4 + rfrag;

    // ---- stage A: P = W*S^T, Yq = Q*S^T; G = U - P -> gt ----
    f32x4 p = {};
    f32x4 yac = {};
#pragma unroll
    for (int ks = 0; ks < 2; ++ks) {
      bf16x8 afw = *(const bf16x8*)(bp + 8192 + swz128(ta, ks * 64 + koff * 2));
      bf16x8 afq = *(const bf16x8*)(bp + swz128(ta, ks * 64 + koff * 2));
      bf16x8 bS = *(const bf16x8*)(ssb + swz128(rfrag, ks * 64 + koff * 2));
      p = __builtin_amdgcn_mfma_f32_16x16x32_bf16(afw, bS, p, 0, 0, 0);
      yac = __builtin_amdgcn_mfma_f32_16x16x32_bf16(afq, bS, yac, 0, 0, 0);
    }
#pragma unroll
    for (int r = 0; r < 4; ++r) {
      int t = 16 * w4 + crow + r;
      float gg = bf2f(*(const unsigned short*)(up + (t * 16 + rfrag) * 2)) - p[r];
      *(unsigned short*)(gt + swz128(rfrag, 2 * t)) = f2bf(gg);
    }
    LDS_BARRIER();   // #2: GT produced -> consumed

    // ---- stage B: Y += SL*G ; S += G^T*K ; stage c+1 (overlapped) ----
#pragma unroll
    for (int ks = 0; ks < 2; ++ks) {
      bf16x8 aSL = *(const bf16x8*)(bp + 16384 + swz128(ta, ks * 64 + koff * 2));
      bf16x8 bGT = *(const bf16x8*)(gt + swz128(rfrag, ks * 64 + koff * 2));
      yac = __builtin_amdgcn_mfma_f32_16x16x32_bf16(aSL, bGT, yac, 0, 0, 0);
    }
#pragma unroll
    for (int ks = 0; ks < 2; ++ks) {
      bf16x8 aGT = *(const bf16x8*)(gt + swz128(rfrag, ks * 64 + koff * 2));
      bf16x8 bKT = *(const bf16x8*)(bp + 24576 + swz128(16 * w4 + rfrag, ks * 64 + koff * 2));
      sacc = __builtin_amdgcn_mfma_f32_16x16x32_bf16(aGT, bKT, sacc, 0, 0, 0);
    }
#pragma unroll
    for (int r = 0; r < 4; ++r) {
      int t = 16 * w4 + crow + r;
      ybuf[(long)(b * 2048 + c * 64 + t) * 1024 + h * 64 + dq * 16 + rfrag] = f2bf(yac[r]);
    }
#pragma unroll
    for (int r = 0; r < 4; ++r)
      *(unsigned short*)(ssb + swz128(crow + r, 2 * (16 * w4 + rfrag))) = f2bf(sacc[r]);
    if (c + 1 < NC_) {
      WRITE_TILES(cur ^ 1);
      int cn = c + 2; if (cn > NC_ - 1) cn = NC_ - 1;
      LOADREGS(cn);
    }
    LDS_BARRIER();   // boundary: tiles staged + sS ready; reads of buf[cur] done
  }

#pragma unroll
  for (int r = 0; r < 4; ++r)
    state_out[(long)bh * 4096 + (dq * 16 + crow + r) * 64 + 16 * w4 + rfrag] = sacc[r];
#undef LOADREGS
#undef WRITE_TILES
}

// ---------------- launch ----------------
extern "C" void kernel_launch(void* const* d_in, const int* in_sizes, int n_in,
                              void* d_out, int out_size, void* d_ws, size_t ws_size,
                              hipStream_t stream) {
  (void)in_sizes; (void)n_in; (void)out_size; (void)ws_size;
  const float* x     = (const float*)d_in[0];
  const float* Wq    = (const float*)d_in[1];
  const float* Wk    = (const float*)d_in[2];
  const float* Wv    = (const float*)d_in[3];
  const float* Wproj = (const float*)d_in[4];
  const float* a_raw = (const float*)d_in[5];
  const float* b_raw = (const float*)d_in[6];
  const float* state = (const float*)d_in[7];

  char* ws = (char*)d_ws;
  unsigned short* xbf = (unsigned short*)ws;                    // 16MB; reused as y
  unsigned short* W3  = (unsigned short*)(ws + (16l << 20));    // 6MB [Wq;Wk;Wv]
  unsigned short* Wp  = (unsigned short*)(ws + (22l << 20));    // 2MB
  unsigned short* qkv = (unsigned short*)(ws + (24l << 20));    // 48MB
  unsigned short* Ub  = (unsigned short*)(ws + (72l << 20));    // 16MB
  unsigned short* Wb  = (unsigned short*)(ws + (88l << 20));    // 16MB
  unsigned short* SLb = (unsigned short*)(ws + (104l << 20));   // 16MB -> 120MB total
  float* out = (float*)d_out;
  float* state_out = out + (long)B_ * T_ * C_;

  cvt_all<<<dim3(12288), dim3(256), 0, stream>>>(x, Wq, Wk, Wv, Wproj, xbf, W3, Wp);

  gemm256_bt<<<dim3(3072 / 256, 8192 / 256), dim3(512), 0, stream>>>(xbf, W3, qkv, 3072);

  chunk_prep<<<dim3(2048), dim3(256), 0, stream>>>(qkv, a_raw, b_raw, Ub, Wb, SLb);
  chunk_scan<<<dim3(64), dim3(1024), 0, stream>>>(qkv, Ub, Wb, SLb, state, xbf, state_out);

  gemm_bt<0><<<dim3(1024 / 128, 8192 / 128), dim3(256), 0, stream>>>(xbf, Wp, (void*)out, 8192, 1024, 1024);
}

// Round 14
// 176.607 us; speedup vs baseline: 1.1002x; 1.1002x over previous
//
#include <hip/hip_runtime.h>
#include <hip/hip_bf16.h>
#include <cstdint>

#define B_ 4
#define T_ 2048
#define C_ 1024
#define H_ 16
#define D_ 64
#define NC_ 32   // chunks
#define L_ 64    // chunk length

typedef __attribute__((ext_vector_type(8))) short bf16x8;
typedef __attribute__((ext_vector_type(4))) float f32x4;

static __device__ __forceinline__ unsigned short f2bf(float f) {
  unsigned u = __float_as_uint(f);
  u += 0x7fff + ((u >> 16) & 1);   // round-to-nearest-even
  return (unsigned short)(u >> 16);
}
static __device__ __forceinline__ float bf2f(unsigned short b) {
  return __uint_as_float(((unsigned)b) << 16);
}
// XOR swizzle for 128B-stride LDS rows (T2): keeps 16B alignment, <=2-way conflicts
static __device__ __forceinline__ int swz128(int row, int byte) {
  return row * 128 + (byte ^ ((row & 7) << 4));
}

// Barrier that does NOT drain vmcnt (T4): LDS edges fenced via lgkmcnt(0).
#define LDS_BARRIER() asm volatile("s_waitcnt lgkmcnt(0)\ns_barrier" ::: "memory")
#define VMCNT0 asm volatile("s_waitcnt vmcnt(0)" ::: "memory");

// ---------------- f32 -> bf16 convert (x + 4 weights in ONE launch) ----------------
__global__ __launch_bounds__(256) void cvt_all(const float* __restrict__ x,
                                               const float* __restrict__ wq,
                                               const float* __restrict__ wk,
                                               const float* __restrict__ wv,
                                               const float* __restrict__ wp,
                                               unsigned short* __restrict__ xbf,
                                               unsigned short* __restrict__ W3,
                                               unsigned short* __restrict__ Wp) {
  const int bidx = blockIdx.x;
  const float* src;
  unsigned short* dst;
  long base;
  if (bidx < 8192) {
    src = x; dst = xbf; base = (long)bidx * 1024;
  } else {
    const int g = (bidx - 8192) >> 10;
    src = (g == 0) ? wq : (g == 1) ? wk : (g == 2) ? wv : wp;
    dst = (g < 3) ? (W3 + (long)g * 1048576) : Wp;
    base = (long)((bidx - 8192) & 1023) * 1024;
  }
  long i = base + threadIdx.x * 4;
  float4 v = *reinterpret_cast<const float4*>(src + i);
  ushort4 o;
  o.x = f2bf(v.x); o.y = f2bf(v.y); o.z = f2bf(v.z); o.w = f2bf(v.w);
  *reinterpret_cast<ushort4*>(dst + i) = o;
}

// ========== 4-phase 128x256 bf16 GEMM (T1+T2+T3+T4+T5), C = A * B^T ==========
// BM=128, BN=256, BK=64, 2 K-tiles/iter, 8 iters (K=1024). 512 thr / 8 waves.
// LDS 96KB: EA 16K | EB 32K | OA 16K | OB 32K.
// Stage placement invariant (fixes R13 race): a region is staged only >=1
// barrier after its last reader. O-regions (read ph2/ph3) staged at ph0;
// E-regions (read ph0/ph1) staged at ph2 (i<7). vmcnt(0) before the closing
// barriers of ph1/ph3 gives the cross-wave landed guarantee one barrier
// before the consuming phase.

#define STAGEH(GP, GR0, KT, LOFF) do {                                            \
    const unsigned short* _s = (GP) + ((GR0) + wid * 8 + lr8) * 1024L             \
                               + (long)(KT) * 64 + skb * 8;                       \
    char* _d = (char*)lds + (LOFF) + wid * 1024;                                  \
    __builtin_amdgcn_global_load_lds((const __attribute__((address_space(1))) void*)_s,      \
        (__attribute__((address_space(3))) void*)_d, 16, 0, 0);                   \
    __builtin_amdgcn_global_load_lds((const __attribute__((address_space(1))) void*)(_s + 64 * 1024L), \
        (__attribute__((address_space(3))) void*)(_d + 8192), 16, 0, 0);          \
  } while (0)

#define PHASE4(AO, BO, NH, STG, ENDVM) do {                                       \
    bf16x8 av[4][2], bv[2][2];                                                    \
    {                                                                             \
      const char* ab = (const char*)lds + (AO) + arow;                            \
      const char* bb = (const char*)lds + (BO) + (NH) * 16384 + brow;             \
      _Pragma("unroll")                                                           \
      for (int j = 0; j < 4; ++j) {                                               \
        av[j][0] = *(const bf16x8*)(ab + j * 4096 + cb0);                         \
        av[j][1] = *(const bf16x8*)(ab + j * 4096 + cb1);                         \
      }                                                                           \
      _Pragma("unroll")                                                           \
      for (int j2 = 0; j2 < 2; ++j2) {                                            \
        bv[j2][0] = *(const bf16x8*)(bb + j2 * 8192 + cb0);                       \
        bv[j2][1] = *(const bf16x8*)(bb + j2 * 8192 + cb1);                       \
      }                                                                           \
    }                                                                             \
    STG;                                                                          \
    __builtin_amdgcn_s_barrier();                                                 \
    asm volatile("s_waitcnt lgkmcnt(0)" ::: "memory");                            \
    __builtin_amdgcn_sched_barrier(0);                                            \
    __builtin_amdgcn_s_setprio(1);                                                \
    _Pragma("unroll")                                                             \
    for (int j = 0; j < 4; ++j)                                                   \
      _Pragma("unroll")                                                           \
      for (int j2 = 0; j2 < 2; ++j2)                                              \
        acc[j][(NH) * 2 + j2] = __builtin_amdgcn_mfma_f32_16x16x32_bf16(          \
            av[j][0], bv[j2][0], acc[j][(NH) * 2 + j2], 0, 0, 0);                 \
    _Pragma("unroll")                                                             \
    for (int j = 0; j < 4; ++j)                                                   \
      _Pragma("unroll")                                                           \
      for (int j2 = 0; j2 < 2; ++j2)                                              \
        acc[j][(NH) * 2 + j2] = __builtin_amdgcn_mfma_f32_16x16x32_bf16(          \
            av[j][1], bv[j2][1], acc[j][(NH) * 2 + j2], 0, 0, 0);                 \
    __builtin_amdgcn_s_setprio(0);                                                \
    ENDVM                                                                         \
    __builtin_amdgcn_s_barrier();                                                 \
  } while (0)

template<int OUT_BF16>
__global__ __launch_bounds__(512, 2) void gemm128x256(
    const unsigned short* __restrict__ A,
    const unsigned short* __restrict__ Bw,
    void* __restrict__ Cp, int N) {
  __shared__ __align__(16) char lds[98304];
  enum { EA = 0, EB = 16384, OA = 49152, OB = 65536 };
  const int tid = threadIdx.x;
  const int wid = tid >> 6, lane = tid & 63;
  const int wm = wid >> 2, wn = wid & 3;
  const int f = lane & 15, g = lane >> 4;
  const int lr8 = lane >> 3, lc = lane & 7;
  const int skb = lc ^ lr8;                 // pre-swizzled source col-block
  // T1: bijective XCD-chunked swizzle (both grids % 8 == 0)
  const int bid = blockIdx.y * gridDim.x + blockIdx.x;
  const int cpx = (gridDim.x * gridDim.y) >> 3;
  const int sw = (bid & 7) * cpx + (bid >> 3);
  const long bM = (long)(sw / gridDim.x) * 128;
  const long bN = (long)(sw % gridDim.x) * 256;
  const int cb0 = ((0 + g) ^ (f & 7)) * 16;
  const int cb1 = ((4 + g) ^ (f & 7)) * 16;
  const int arow = (wm * 16 + f) * 128;
  const int brow = (wn * 16 + f) * 128;

  f32x4 acc[4][4] = {};

  // prologue: stage E = tile 0; drain; barrier
  STAGEH(Bw, bN, 0, EB);
  STAGEH(Bw, bN + 128, 0, EB + 16384);
  STAGEH(A, bM, 0, EA);
  VMCNT0
  __builtin_amdgcn_s_barrier();

  for (int i = 0; i < 8; ++i) {
    const int to = 2 * i + 1;       // O tile, staged at ph0, read ph2/ph3
    const int te = 2 * i + 2;       // E tile, staged at ph2 (i<7), read next ph0/ph1
    PHASE4(EA, EB, 0,
           { STAGEH(Bw, bN, to, OB); STAGEH(Bw, bN + 128, to, OB + 16384); STAGEH(A, bM, to, OA); },
           );
    PHASE4(EA, EB, 1, {}, VMCNT0);
    PHASE4(OA, OB, 0,
           { if (i < 7) { STAGEH(Bw, bN, te, EB); STAGEH(Bw, bN + 128, te, EB + 16384); STAGEH(A, bM, te, EA); } },
           );
    PHASE4(OA, OB, 1, {}, VMCNT0);
  }

  // epilogue
#pragma unroll
  for (int mf = 0; mf < 4; ++mf) {
    long row = bM + mf * 32 + wm * 16 + g * 4;
#pragma unroll
    for (int nf = 0; nf < 4; ++nf) {
      long col = bN + (nf >> 1) * 128 + (nf & 1) * 64 + wn * 16 + f;
#pragma unroll
      for (int r = 0; r < 4; ++r) {
        if (OUT_BF16)
          ((unsigned short*)Cp)[(row + r) * (long)N + col] = f2bf(acc[mf][nf][r]);
        else
          ((float*)Cp)[(row + r) * (long)N + col] = acc[mf][nf][r];
      }
    }
  }
}

// ---------------- phase 1: per (bh, chunk) WY precompute ----------------
// Packs KT = K_norm^T into the dead V-slot of qkv (scan stages it vectorized).
__global__ __launch_bounds__(256) void chunk_prep(
    unsigned short* __restrict__ qkv,
    const float* __restrict__ a_raw, const float* __restrict__ b_raw,
    unsigned short* __restrict__ Ubuf, unsigned short* __restrict__ Wbuf,
    unsigned short* __restrict__ SLbuf) {
  __shared__ __align__(16) unsigned short sK[64 * 64];
  __shared__ __align__(16) unsigned short sQ[64 * 64];
  __shared__ __align__(16) unsigned short sV[64 * 64];
  __shared__ float sA[64 * 64];

  const int blk = blockIdx.x;           // bh*32 + c
  const int bh = blk >> 5, c = blk & 31;
  const int b = bh >> 4, h = bh & 15;
  const int tid = threadIdx.x;
  const int wid = tid >> 6, lane = tid & 63;

  const float alpha = 0.5f / (1.f + __expf(-a_raw[h]));
  const float beta  = 0.5f / (1.f + __expf(-b_raw[h]));

  {
    const int row = tid >> 2, cg = tid & 3;
    unsigned short* gp = qkv + (long)(b * 2048 + c * 64 + row) * 3072 + h * 64 + cg * 16;
    bf16x8 q0 = *(const bf16x8*)(gp);
    bf16x8 q1 = *(const bf16x8*)(gp + 8);
    bf16x8 k0 = *(const bf16x8*)(gp + 1024);
    bf16x8 k1 = *(const bf16x8*)(gp + 1024 + 8);
    bf16x8 v0 = *(const bf16x8*)(gp + 2048);
    bf16x8 v1 = *(const bf16x8*)(gp + 2048 + 8);
    float kf[16];
    float ss = 0.f;
#pragma unroll
    for (int i = 0; i < 8; ++i) { kf[i] = bf2f((unsigned short)k0[i]); ss += kf[i] * kf[i]; }
#pragma unroll
    for (int i = 0; i < 8; ++i) { kf[8 + i] = bf2f((unsigned short)k1[i]); ss += kf[8 + i] * kf[8 + i]; }
    ss += __shfl_xor(ss, 1);
    ss += __shfl_xor(ss, 2);
    const float inv = 1.f / fmaxf(sqrtf(ss), 1e-12f);
    bf16x8 n0, n1;
#pragma unroll
    for (int i = 0; i < 8; ++i) { n0[i] = (short)f2bf(kf[i] * inv); n1[i] = (short)f2bf(kf[8 + i] * inv); }
    *(bf16x8*)((char*)sK + swz128(row, cg * 32)) = n0;
    *(bf16x8*)((char*)sK + swz128(row, cg * 32 + 16)) = n1;
    *(bf16x8*)((char*)sQ + swz128(row, cg * 32)) = q0;
    *(bf16x8*)((char*)sQ + swz128(row, cg * 32 + 16)) = q1;
    *(bf16x8*)((char*)sV + row * 128 + cg * 32) = v0;
    *(bf16x8*)((char*)sV + row * 128 + cg * 32 + 16) = v1;
  }
  __syncthreads();

  // KT pack: slot[e][t] = K_norm[t][e] -> qkv V-slot (coalesced bf16x8 stores)
  {
    const int erow = tid >> 2, tq = tid & 3;
    unsigned short kt[16];
#pragma unroll
    for (int i = 0; i < 16; ++i)
      kt[i] = *(const unsigned short*)((const char*)sK + swz128(tq * 16 + i, 2 * erow));
    unsigned short* vp = qkv + (long)(b * 2048 + c * 64 + erow) * 3072 + 2048 + h * 64 + tq * 16;
    *(bf16x8*)vp = *(const bf16x8*)kt;
    *(bf16x8*)(vp + 8) = *(const bf16x8*)(kt + 8);
  }

  const int rfrag = lane & 15, koff = (lane >> 4) * 8, crow = (lane >> 4) * 4;
  const int w2 = wid & 1;
  if (wid < 2) {
#pragma unroll
    for (int mt = 0; mt < 2; ++mt) {
      const int m = w2 * 2 + mt;
      const int ra = 16 * m + rfrag;
      f32x4 acc[4] = {};
#pragma unroll
      for (int ks = 0; ks < 2; ++ks) {
        bf16x8 af = *(const bf16x8*)((const char*)sK + swz128(ra, ks * 64 + koff * 2));
#pragma unroll
        for (int n = 0; n < 4; ++n) {
          bf16x8 bf = *(const bf16x8*)((const char*)sK + swz128(16 * n + rfrag, ks * 64 + koff * 2));
          acc[n] = __builtin_amdgcn_mfma_f32_16x16x32_bf16(af, bf, acc[n], 0, 0, 0);
        }
      }
#pragma unroll
      for (int n = 0; n < 4; ++n)
#pragma unroll
        for (int r = 0; r < 4; ++r)
          sA[(16 * m + crow + r) * 64 + 16 * n + rfrag] = acc[n][r];
    }
  } else {
#pragma unroll
    for (int mt = 0; mt < 2; ++mt) {
      const int m = w2 * 2 + mt;
      const int ra = 16 * m + rfrag;
      f32x4 acc[4] = {};
#pragma unroll
      for (int ks = 0; ks < 2; ++ks) {
        bf16x8 af = *(const bf16x8*)((const char*)sQ + swz128(ra, ks * 64 + koff * 2));
#pragma unroll
        for (int n = 0; n < 4; ++n) {
          bf16x8 bf = *(const bf16x8*)((const char*)sK + swz128(16 * n + rfrag, ks * 64 + koff * 2));
          acc[n] = __builtin_amdgcn_mfma_f32_16x16x32_bf16(af, bf, acc[n], 0, 0, 0);
        }
      }
#pragma unroll
      for (int n = 0; n < 4; ++n)
#pragma unroll
        for (int r = 0; r < 4; ++r) {
          int t = 16 * m + crow + r, j = 16 * n + rfrag;
          SLbuf[(long)blk * 4096 + t * 64 + j] = (j < t) ? f2bf(acc[n][r]) : (unsigned short)0;
        }
    }
  }
  __syncthreads();

  if (wid < 2) {
    const int d = lane;
    float x[64];
#pragma unroll
    for (int t = 0; t < 64; ++t) {
      float rhs;
      if (wid == 0) rhs = beta * bf2f(sV[t * 64 + d]);
      else          rhs = alpha * bf2f(*(const unsigned short*)((const char*)sK + swz128(t, 2 * d)));
      float s = 0.f;
#pragma unroll
      for (int j = 0; j < t; ++j) s = fmaf(sA[t * 64 + j], x[j], s);
      x[t] = rhs - alpha * s;
    }
    unsigned short* ob = (wid == 0 ? Ubuf : Wbuf) + (long)blk * 4096 + d;
#pragma unroll
    for (int t = 0; t < 64; ++t) ob[t * 64] = f2bf(x[t]);
  }
}

// ---------------- phase 2: sequential chunk recurrence (R11 best version) ----------------
__global__ __launch_bounds__(256) void chunk_scan(
    const unsigned short* __restrict__ qkv,
    const unsigned short* __restrict__ Ubuf, const unsigned short* __restrict__ Wbuf,
    const unsigned short* __restrict__ SLbuf,
    const float* __restrict__ state_in, unsigned short* __restrict__ ybuf,
    float* __restrict__ state_out) {
  // layout (bytes): buf k at k*34816: Q+0, W+8192, SL+16384, KT+24576, U+32768(2KB)
  // sGT at 69632 (2KB), sS at 71680 (2KB) -> 72KB total
  __shared__ __align__(16) char lds[73728];

  const int bid0 = blockIdx.x;
  const int blk = (bid0 & 7) * 32 + (bid0 >> 3);   // T1 (256 % 8 == 0)
  const int bh = blk >> 2, dq = blk & 3;
  const int b = bh >> 4, h = bh & 15;
  const int tid = threadIdx.x, wid = tid >> 6, lane = tid & 63;
  const int rfrag = lane & 15, koff = (lane >> 4) * 8, crow = (lane >> 4) * 4;
  const int row = tid >> 2, cg = tid & 3;

  char* gt = lds + 69632;
  char* ssb = lds + 71680;

  const unsigned short* gpb = qkv + (long)(b * 2048 + row) * 3072 + h * 64 + cg * 16;
  const long tbb = ((long)(bh * 32) * 64 + row) * 64 + cg * 16;
  const long ubb = ((long)(bh * 32) * 64 + (tid >> 1)) * 64 + dq * 16 + (tid & 1) * 8;

  bf16x8 qv0, qv1, kt0, kt1, wv0, wv1, sl0, sl1, uv;
#define LOADREGS(CN) do {                                                       \
    const unsigned short* gp = gpb + (long)(CN) * 64 * 3072;                    \
    const long tb = tbb + (long)(CN) * 4096;                                    \
    qv0 = *(const bf16x8*)gp;            qv1 = *(const bf16x8*)(gp + 8);        \
    kt0 = *(const bf16x8*)(gp + 2048);   kt1 = *(const bf16x8*)(gp + 2048 + 8); \
    wv0 = *(const bf16x8*)(Wbuf + tb);   wv1 = *(const bf16x8*)(Wbuf + tb + 8); \
    sl0 = *(const bf16x8*)(SLbuf + tb);  sl1 = *(const bf16x8*)(SLbuf + tb + 8);\
    if (tid < 128) uv = *(const bf16x8*)(Ubuf + ubb + (long)(CN) * 4096);       \
  } while (0)

#define WRITE_TILES(BUF) do {                                                   \
    char* bp_ = lds + (BUF) * 34816;                                            \
    *(bf16x8*)(bp_ + swz128(row, cg * 32)) = qv0;                               \
    *(bf16x8*)(bp_ + swz128(row, cg * 32 + 16)) = qv1;                          \
    *(bf16x8*)(bp_ + 8192 + swz128(row, cg * 32)) = wv0;                        \
    *(bf16x8*)(bp_ + 8192 + swz128(row, cg * 32 + 16)) = wv1;                   \
    *(bf16x8*)(bp_ + 16384 + swz128(row, cg * 32)) = sl0;                       \
    *(bf16x8*)(bp_ + 16384 + swz128(row, cg * 32 + 16)) = sl1;                  \
    *(bf16x8*)(bp_ + 24576 + swz128(row, cg * 32)) = kt0;                       \
    *(bf16x8*)(bp_ + 24576 + swz128(row, cg * 32 + 16)) = kt1;                  \
    if (tid < 128) *(bf16x8*)(bp_ + 32768 + ((tid >> 1) * 16 + (tid & 1) * 8) * 2) = uv; \
  } while (0)

  f32x4 sacc;
#pragma unroll
  for (int r = 0; r < 4; ++r)
    sacc[r] = state_in[(long)bh * 4096 + (dq * 16 + crow + r) * 64 + 16 * wid + rfrag];
#pragma unroll
  for (int r = 0; r < 4; ++r)
    *(unsigned short*)(ssb + swz128(crow + r, 2 * (16 * wid + rfrag))) = f2bf(sacc[r]);

  // prologue: stage chunk 0 into buf0; prefetch chunk 1 regs
  LOADREGS(0);
  WRITE_TILES(0);
  LOADREGS(1);
  LDS_BARRIER();

  for (int c = 0; c < NC_; ++c) {
    const int cur = c & 1;
    const char* bp = lds + cur * 34816;
    const int ta = 16 * wid + rfrag;

    // ---- stage A: P = W*S^T, Yq = Q*S^T; G = U - P -> sGT ----
    f32x4 p = {};
    f32x4 yac = {};
#pragma unroll
    for (int ks = 0; ks < 2; ++ks) {
      bf16x8 afw = *(const bf16x8*)(bp + 8192 + swz128(ta, ks * 64 + koff * 2));
      bf16x8 afq = *(const bf16x8*)(bp + swz128(ta, ks * 64 + koff * 2));
      bf16x8 bS = *(const bf16x8*)(ssb + swz128(rfrag, ks * 64 + koff * 2));
      p = __builtin_amdgcn_mfma_f32_16x16x32_bf16(afw, bS, p, 0, 0, 0);
      yac = __builtin_amdgcn_mfma_f32_16x16x32_bf16(afq, bS, yac, 0, 0, 0);
    }
#pragma unroll
    for (int r = 0; r < 4; ++r) {
      int t = 16 * wid + crow + r;
      float gg = bf2f(*(const unsigned short*)(bp + 32768 + (t * 16 + rfrag) * 2)) - p[r];
      *(unsigned short*)(gt + swz128(rfrag, 2 * t)) = f2bf(gg);
    }
    LDS_BARRIER();   // #2: GT produced -> consumed

    // ---- stage B: Y += SL*G ; S += G^T*K ; stage c+1 tiles (overlapped) ----
#pragma unroll
    for (int ks = 0; ks < 2; ++ks) {
      bf16x8 aSL = *(const bf16x8*)(bp + 16384 + swz128(ta, ks * 64 + koff * 2));
      bf16x8 bGT = *(const bf16x8*)(gt + swz128(rfrag, ks * 64 + koff * 2));
      yac = __builtin_amdgcn_mfma_f32_16x16x32_bf16(aSL, bGT, yac, 0, 0, 0);
    }
#pragma unroll
    for (int ks = 0; ks < 2; ++ks) {
      bf16x8 aGT = *(const bf16x8*)(gt + swz128(rfrag, ks * 64 + koff * 2));
      bf16x8 bKT = *(const bf16x8*)(bp + 24576 + swz128(16 * wid + rfrag, ks * 64 + koff * 2));
      sacc = __builtin_amdgcn_mfma_f32_16x16x32_bf16(aGT, bKT, sacc, 0, 0, 0);
    }
#pragma unroll
    for (int r = 0; r < 4; ++r) {
      int t = 16 * wid + crow + r;
      ybuf[(long)(b * 2048 + c * 64 + t) * 1024 + h * 64 + dq * 16 + rfrag] = f2bf(yac[r]);
    }
    // new S -> sS (read at next chunk's stage A, after boundary barrier)
#pragma unroll
    for (int r = 0; r < 4; ++r)
      *(unsigned short*)(ssb + swz128(crow + r, 2 * (16 * wid + rfrag))) = f2bf(sacc[r]);
    // stage chunk c+1 tiles into the other buffer; prefetch chunk c+2
    if (c + 1 < NC_) {
      WRITE_TILES(cur ^ 1);
      int cn = c + 2; if (cn > NC_ - 1) cn = NC_ - 1;
      LOADREGS(cn);
    }
    LDS_BARRIER();   // boundary: tiles staged + sS ready; reads of buf[cur] done
  }

#pragma unroll
  for (int r = 0; r < 4; ++r)
    state_out[(long)bh * 4096 + (dq * 16 + crow + r) * 64 + 16 * wid + rfrag] = sacc[r];
#undef LOADREGS
#undef WRITE_TILES
}

// ---------------- launch ----------------
extern "C" void kernel_launch(void* const* d_in, const int* in_sizes, int n_in,
                              void* d_out, int out_size, void* d_ws, size_t ws_size,
                              hipStream_t stream) {
  (void)in_sizes; (void)n_in; (void)out_size; (void)ws_size;
  const float* x     = (const float*)d_in[0];
  const float* Wq    = (const float*)d_in[1];
  const float* Wk    = (const float*)d_in[2];
  const float* Wv    = (const float*)d_in[3];
  const float* Wproj = (const float*)d_in[4];
  const float* a_raw = (const float*)d_in[5];
  const float* b_raw = (const float*)d_in[6];
  const float* state = (const float*)d_in[7];

  char* ws = (char*)d_ws;
  unsigned short* xbf = (unsigned short*)ws;                    // 16MB; reused as y
  unsigned short* W3  = (unsigned short*)(ws + (16l << 20));    // 6MB [Wq;Wk;Wv]
  unsigned short* Wp  = (unsigned short*)(ws + (22l << 20));    // 2MB
  unsigned short* qkv = (unsigned short*)(ws + (24l << 20));    // 48MB
  unsigned short* Ub  = (unsigned short*)(ws + (72l << 20));    // 16MB
  unsigned short* Wb  = (unsigned short*)(ws + (88l << 20));    // 16MB
  unsigned short* SLb = (unsigned short*)(ws + (104l << 20));   // 16MB -> 120MB total
  float* out = (float*)d_out;
  float* state_out = out + (long)B_ * T_ * C_;

  cvt_all<<<dim3(12288), dim3(256), 0, stream>>>(x, Wq, Wk, Wv, Wproj, xbf, W3, Wp);

  // QKV projection: 768 blocks = 3 exact CU-rounds
  gemm128x256<1><<<dim3(3072 / 256, 8192 / 128), dim3(512), 0, stream>>>(xbf, W3, (void*)qkv, 3072);

  chunk_prep<<<dim3(2048), dim3(256), 0, stream>>>(qkv, a_raw, b_raw, Ub, Wb, SLb);
  chunk_scan<<<dim3(256), dim3(256), 0, stream>>>(qkv, Ub, Wb, SLb, state, xbf, state_out);

  // out projection: 256 blocks = 1 exact CU-round, f32 out
  gemm128x256<0><<<dim3(1024 / 256, 8192 / 128), dim3(512), 0, stream>>>(xbf, Wp, (void*)out, 1024);
}

// Round 15
// 174.809 us; speedup vs baseline: 1.1115x; 1.0103x over previous
//
#include <hip/hip_runtime.h>
#include <hip/hip_bf16.h>
#include <cstdint>

#define B_ 4
#define T_ 2048
#define C_ 1024
#define H_ 16
#define D_ 64
#define NC_ 32   // chunks
#define L_ 64    // chunk length

typedef __attribute__((ext_vector_type(8))) short bf16x8;
typedef __attribute__((ext_vector_type(4))) float f32x4;

static __device__ __forceinline__ unsigned short f2bf(float f) {
  unsigned u = __float_as_uint(f);
  u += 0x7fff + ((u >> 16) & 1);   // round-to-nearest-even
  return (unsigned short)(u >> 16);
}
static __device__ __forceinline__ float bf2f(unsigned short b) {
  return __uint_as_float(((unsigned)b) << 16);
}
// XOR swizzle for 128B-stride LDS rows (T2): keeps 16B alignment, <=2-way conflicts
static __device__ __forceinline__ int swz128(int row, int byte) {
  return row * 128 + (byte ^ ((row & 7) << 4));
}

// Barrier that does NOT drain vmcnt (T4): LDS edges fenced via lgkmcnt(0).
#define LDS_BARRIER() asm volatile("s_waitcnt lgkmcnt(0)\ns_barrier" ::: "memory")

// ---------------- f32 -> bf16 convert (x + 4 weights in ONE launch) ----------------
__global__ __launch_bounds__(256) void cvt_all(const float* __restrict__ x,
                                               const float* __restrict__ wq,
                                               const float* __restrict__ wk,
                                               const float* __restrict__ wv,
                                               const float* __restrict__ wp,
                                               unsigned short* __restrict__ xbf,
                                               unsigned short* __restrict__ W3,
                                               unsigned short* __restrict__ Wp) {
  const int bidx = blockIdx.x;
  const float* src;
  unsigned short* dst;
  long base;
  if (bidx < 8192) {
    src = x; dst = xbf; base = (long)bidx * 1024;
  } else {
    const int g = (bidx - 8192) >> 10;
    src = (g == 0) ? wq : (g == 1) ? wk : (g == 2) ? wv : wp;
    dst = (g < 3) ? (W3 + (long)g * 1048576) : Wp;
    base = (long)((bidx - 8192) & 1023) * 1024;
  }
  long i = base + threadIdx.x * 4;
  float4 v = *reinterpret_cast<const float4*>(src + i);
  ushort4 o;
  o.x = f2bf(v.x); o.y = f2bf(v.y); o.z = f2bf(v.z); o.w = f2bf(v.w);
  *reinterpret_cast<ushort4*>(dst + i) = o;
}

// ========== 128x256 bf16 GEMM, 3-region LDS rotation (T1..T5), C = A * B^T ==========
// BM=128, BN=256, BK=64, 16 K-tiles (K=1024). 512 thr / 8 waves. LDS 144KB =
// 3 regions x 48KB {A 16K | B 32K}; tile t uses region t%3. Tile t+2 staged at
// tile t phase A; drained by COUNTED vmcnt(6) at tile t phase B end (waits only
// tile t+1's 6 loads; stage->drain distance ~3 phases > HBM latency). Ghost
// stages (ts clamp) keep vmcnt uniform; they land in dead regions, never read.

#define STAGEH(GP, GR0, KT, LOFF) do {                                            \
    const unsigned short* _s = (GP) + ((GR0) + wid * 8 + lr8) * 1024L             \
                               + (long)(KT) * 64 + skb * 8;                       \
    char* _d = (char*)lds + (LOFF) + wid * 1024;                                  \
    __builtin_amdgcn_global_load_lds((const __attribute__((address_space(1))) void*)_s,      \
        (__attribute__((address_space(3))) void*)_d, 16, 0, 0);                   \
    __builtin_amdgcn_global_load_lds((const __attribute__((address_space(1))) void*)(_s + 64 * 1024L), \
        (__attribute__((address_space(3))) void*)(_d + 8192), 16, 0, 0);          \
  } while (0)

#define PHASE3(RG, NH, STG, ENDVM) do {                                           \
    bf16x8 av[4][2], bv[2][2];                                                    \
    {                                                                             \
      const char* ab = (const char*)lds + (RG) + arow;                            \
      const char* bb = (const char*)lds + (RG) + 16384 + (NH) * 16384 + brow;     \
      _Pragma("unroll")                                                           \
      for (int j = 0; j < 4; ++j) {                                               \
        av[j][0] = *(const bf16x8*)(ab + j * 4096 + cb0);                         \
        av[j][1] = *(const bf16x8*)(ab + j * 4096 + cb1);                         \
      }                                                                           \
      _Pragma("unroll")                                                           \
      for (int j2 = 0; j2 < 2; ++j2) {                                            \
        bv[j2][0] = *(const bf16x8*)(bb + j2 * 8192 + cb0);                       \
        bv[j2][1] = *(const bf16x8*)(bb + j2 * 8192 + cb1);                       \
      }                                                                           \
    }                                                                             \
    STG;                                                                          \
    __builtin_amdgcn_s_barrier();                                                 \
    asm volatile("s_waitcnt lgkmcnt(0)" ::: "memory");                            \
    __builtin_amdgcn_sched_barrier(0);                                            \
    __builtin_amdgcn_s_setprio(1);                                                \
    _Pragma("unroll")                                                             \
    for (int j = 0; j < 4; ++j)                                                   \
      _Pragma("unroll")                                                           \
      for (int j2 = 0; j2 < 2; ++j2)                                              \
        acc[j][(NH) * 2 + j2] = __builtin_amdgcn_mfma_f32_16x16x32_bf16(          \
            av[j][0], bv[j2][0], acc[j][(NH) * 2 + j2], 0, 0, 0);                 \
    _Pragma("unroll")                                                             \
    for (int j = 0; j < 4; ++j)                                                   \
      _Pragma("unroll")                                                           \
      for (int j2 = 0; j2 < 2; ++j2)                                              \
        acc[j][(NH) * 2 + j2] = __builtin_amdgcn_mfma_f32_16x16x32_bf16(          \
            av[j][1], bv[j2][1], acc[j][(NH) * 2 + j2], 0, 0, 0);                 \
    __builtin_amdgcn_s_setprio(0);                                                \
    ENDVM                                                                         \
    __builtin_amdgcn_s_barrier();                                                 \
  } while (0)

template<int OUT_BF16>
__global__ __launch_bounds__(512, 2) void gemm128x256(
    const unsigned short* __restrict__ A,
    const unsigned short* __restrict__ Bw,
    void* __restrict__ Cp, int N) {
  __shared__ __align__(16) char lds[147456];   // 3 x 48KB regions
  const int tid = threadIdx.x;
  const int wid = tid >> 6, lane = tid & 63;
  const int wm = wid >> 2, wn = wid & 3;
  const int f = lane & 15, g = lane >> 4;
  const int lr8 = lane >> 3, lc = lane & 7;
  const int skb = lc ^ lr8;                 // pre-swizzled source col-block
  // T1: bijective XCD-chunked swizzle (both grids % 8 == 0)
  const int bid = blockIdx.y * gridDim.x + blockIdx.x;
  const int cpx = (gridDim.x * gridDim.y) >> 3;
  const int sw = (bid & 7) * cpx + (bid >> 3);
  const long bM = (long)(sw / gridDim.x) * 128;
  const long bN = (long)(sw % gridDim.x) * 256;
  const int cb0 = ((0 + g) ^ (f & 7)) * 16;
  const int cb1 = ((4 + g) ^ (f & 7)) * 16;
  const int arow = (wm * 16 + f) * 128;
  const int brow = (wn * 16 + f) * 128;

  f32x4 acc[4][4] = {};

  // prologue: stage tile0 -> R0, tile1 -> R1; wait tile0 landed (counted)
  STAGEH(Bw, bN, 0, 16384);
  STAGEH(Bw, bN + 128, 0, 32768);
  STAGEH(A, bM, 0, 0);
  STAGEH(Bw, bN, 1, 49152 + 16384);
  STAGEH(Bw, bN + 128, 1, 49152 + 32768);
  STAGEH(A, bM, 1, 49152);
  asm volatile("s_waitcnt vmcnt(6)" ::: "memory");
  __builtin_amdgcn_s_barrier();

#pragma unroll
  for (int t = 0; t < 16; ++t) {
    const int rg = (t % 3) * 49152;
    const int ng = ((t + 2) % 3) * 49152;
    const int ts = (t + 2 > 15) ? 15 : t + 2;   // ghost clamp -> dead region
    PHASE3(rg, 0,
           { STAGEH(Bw, bN, ts, ng + 16384); STAGEH(Bw, bN + 128, ts, ng + 32768); STAGEH(A, bM, ts, ng); },
           );
    PHASE3(rg, 1, {},
           asm volatile("s_waitcnt vmcnt(6)" ::: "memory"););
  }
  asm volatile("s_waitcnt vmcnt(0)" ::: "memory");   // drain ghosts before exit

  // epilogue
#pragma unroll
  for (int mf = 0; mf < 4; ++mf) {
    long row = bM + mf * 32 + wm * 16 + g * 4;
#pragma unroll
    for (int nf = 0; nf < 4; ++nf) {
      long col = bN + (nf >> 1) * 128 + (nf & 1) * 64 + wn * 16 + f;
#pragma unroll
      for (int r = 0; r < 4; ++r) {
        if (OUT_BF16)
          ((unsigned short*)Cp)[(row + r) * (long)N + col] = f2bf(acc[mf][nf][r]);
        else
          ((float*)Cp)[(row + r) * (long)N + col] = acc[mf][nf][r];
      }
    }
  }
}

// ---------------- phase 1: per (bh, chunk) WY precompute ----------------
// Packs KT = K_norm^T into the dead V-slot of qkv (scan stages it vectorized).
__global__ __launch_bounds__(256) void chunk_prep(
    unsigned short* __restrict__ qkv,
    const float* __restrict__ a_raw, const float* __restrict__ b_raw,
    unsigned short* __restrict__ Ubuf, unsigned short* __restrict__ Wbuf,
    unsigned short* __restrict__ SLbuf) {
  __shared__ __align__(16) unsigned short sK[64 * 64];
  __shared__ __align__(16) unsigned short sQ[64 * 64];
  __shared__ __align__(16) unsigned short sV[64 * 64];
  __shared__ float sA[64 * 64];

  const int blk = blockIdx.x;           // bh*32 + c
  const int bh = blk >> 5, c = blk & 31;
  const int b = bh >> 4, h = bh & 15;
  const int tid = threadIdx.x;
  const int wid = tid >> 6, lane = tid & 63;

  const float alpha = 0.5f / (1.f + __expf(-a_raw[h]));
  const float beta  = 0.5f / (1.f + __expf(-b_raw[h]));

  {
    const int row = tid >> 2, cg = tid & 3;
    unsigned short* gp = qkv + (long)(b * 2048 + c * 64 + row) * 3072 + h * 64 + cg * 16;
    bf16x8 q0 = *(const bf16x8*)(gp);
    bf16x8 q1 = *(const bf16x8*)(gp + 8);
    bf16x8 k0 = *(const bf16x8*)(gp + 1024);
    bf16x8 k1 = *(const bf16x8*)(gp + 1024 + 8);
    bf16x8 v0 = *(const bf16x8*)(gp + 2048);
    bf16x8 v1 = *(const bf16x8*)(gp + 2048 + 8);
    float kf[16];
    float ss = 0.f;
#pragma unroll
    for (int i = 0; i < 8; ++i) { kf[i] = bf2f((unsigned short)k0[i]); ss += kf[i] * kf[i]; }
#pragma unroll
    for (int i = 0; i < 8; ++i) { kf[8 + i] = bf2f((unsigned short)k1[i]); ss += kf[8 + i] * kf[8 + i]; }
    ss += __shfl_xor(ss, 1);
    ss += __shfl_xor(ss, 2);
    const float inv = 1.f / fmaxf(sqrtf(ss), 1e-12f);
    bf16x8 n0, n1;
#pragma unroll
    for (int i = 0; i < 8; ++i) { n0[i] = (short)f2bf(kf[i] * inv); n1[i] = (short)f2bf(kf[8 + i] * inv); }
    *(bf16x8*)((char*)sK + swz128(row, cg * 32)) = n0;
    *(bf16x8*)((char*)sK + swz128(row, cg * 32 + 16)) = n1;
    *(bf16x8*)((char*)sQ + swz128(row, cg * 32)) = q0;
    *(bf16x8*)((char*)sQ + swz128(row, cg * 32 + 16)) = q1;
    *(bf16x8*)((char*)sV + row * 128 + cg * 32) = v0;
    *(bf16x8*)((char*)sV + row * 128 + cg * 32 + 16) = v1;
  }
  __syncthreads();

  // KT pack: slot[e][t] = K_norm[t][e] -> qkv V-slot (coalesced bf16x8 stores)
  {
    const int erow = tid >> 2, tq = tid & 3;
    unsigned short kt[16];
#pragma unroll
    for (int i = 0; i < 16; ++i)
      kt[i] = *(const unsigned short*)((const char*)sK + swz128(tq * 16 + i, 2 * erow));
    unsigned short* vp = qkv + (long)(b * 2048 + c * 64 + erow) * 3072 + 2048 + h * 64 + tq * 16;
    *(bf16x8*)vp = *(const bf16x8*)kt;
    *(bf16x8*)(vp + 8) = *(const bf16x8*)(kt + 8);
  }

  const int rfrag = lane & 15, koff = (lane >> 4) * 8, crow = (lane >> 4) * 4;
  const int w2 = wid & 1;
  if (wid < 2) {
#pragma unroll
    for (int mt = 0; mt < 2; ++mt) {
      const int m = w2 * 2 + mt;
      const int ra = 16 * m + rfrag;
      f32x4 acc[4] = {};
#pragma unroll
      for (int ks = 0; ks < 2; ++ks) {
        bf16x8 af = *(const bf16x8*)((const char*)sK + swz128(ra, ks * 64 + koff * 2));
#pragma unroll
        for (int n = 0; n < 4; ++n) {
          bf16x8 bf = *(const bf16x8*)((const char*)sK + swz128(16 * n + rfrag, ks * 64 + koff * 2));
          acc[n] = __builtin_amdgcn_mfma_f32_16x16x32_bf16(af, bf, acc[n], 0, 0, 0);
        }
      }
#pragma unroll
      for (int n = 0; n < 4; ++n)
#pragma unroll
        for (int r = 0; r < 4; ++r)
          sA[(16 * m + crow + r) * 64 + 16 * n + rfrag] = acc[n][r];
    }
  } else {
#pragma unroll
    for (int mt = 0; mt < 2; ++mt) {
      const int m = w2 * 2 + mt;
      const int ra = 16 * m + rfrag;
      f32x4 acc[4] = {};
#pragma unroll
      for (int ks = 0; ks < 2; ++ks) {
        bf16x8 af = *(const bf16x8*)((const char*)sQ + swz128(ra, ks * 64 + koff * 2));
#pragma unroll
        for (int n = 0; n < 4; ++n) {
          bf16x8 bf = *(const bf16x8*)((const char*)sK + swz128(16 * n + rfrag, ks * 64 + koff * 2));
          acc[n] = __builtin_amdgcn_mfma_f32_16x16x32_bf16(af, bf, acc[n], 0, 0, 0);
        }
      }
#pragma unroll
      for (int n = 0; n < 4; ++n)
#pragma unroll
        for (int r = 0; r < 4; ++r) {
          int t = 16 * m + crow + r, j = 16 * n + rfrag;
          SLbuf[(long)blk * 4096 + t * 64 + j] = (j < t) ? f2bf(acc[n][r]) : (unsigned short)0;
        }
    }
  }
  __syncthreads();

  if (wid < 2) {
    const int d = lane;
    float x[64];
#pragma unroll
    for (int t = 0; t < 64; ++t) {
      float rhs;
      if (wid == 0) rhs = beta * bf2f(sV[t * 64 + d]);
      else          rhs = alpha * bf2f(*(const unsigned short*)((const char*)sK + swz128(t, 2 * d)));
      float s = 0.f;
#pragma unroll
      for (int j = 0; j < t; ++j) s = fmaf(sA[t * 64 + j], x[j], s);
      x[t] = rhs - alpha * s;
    }
    unsigned short* ob = (wid == 0 ? Ubuf : Wbuf) + (long)blk * 4096 + d;
#pragma unroll
    for (int t = 0; t < 64; ++t) ob[t * 64] = f2bf(x[t]);
  }
}

// ---------------- phase 2: sequential chunk recurrence (R11 best version) ----------------
__global__ __launch_bounds__(256) void chunk_scan(
    const unsigned short* __restrict__ qkv,
    const unsigned short* __restrict__ Ubuf, const unsigned short* __restrict__ Wbuf,
    const unsigned short* __restrict__ SLbuf,
    const float* __restrict__ state_in, unsigned short* __restrict__ ybuf,
    float* __restrict__ state_out) {
  // layout (bytes): buf k at k*34816: Q+0, W+8192, SL+16384, KT+24576, U+32768(2KB)
  // sGT at 69632 (2KB), sS at 71680 (2KB) -> 72KB total
  __shared__ __align__(16) char lds[73728];

  const int bid0 = blockIdx.x;
  const int blk = (bid0 & 7) * 32 + (bid0 >> 3);   // T1 (256 % 8 == 0)
  const int bh = blk >> 2, dq = blk & 3;
  const int b = bh >> 4, h = bh & 15;
  const int tid = threadIdx.x, wid = tid >> 6, lane = tid & 63;
  const int rfrag = lane & 15, koff = (lane >> 4) * 8, crow = (lane >> 4) * 4;
  const int row = tid >> 2, cg = tid & 3;

  char* gt = lds + 69632;
  char* ssb = lds + 71680;

  const unsigned short* gpb = qkv + (long)(b * 2048 + row) * 3072 + h * 64 + cg * 16;
  const long tbb = ((long)(bh * 32) * 64 + row) * 64 + cg * 16;
  const long ubb = ((long)(bh * 32) * 64 + (tid >> 1)) * 64 + dq * 16 + (tid & 1) * 8;

  bf16x8 qv0, qv1, kt0, kt1, wv0, wv1, sl0, sl1, uv;
#define LOADREGS(CN) do {                                                       \
    const unsigned short* gp = gpb + (long)(CN) * 64 * 3072;                    \
    const long tb = tbb + (long)(CN) * 4096;                                    \
    qv0 = *(const bf16x8*)gp;            qv1 = *(const bf16x8*)(gp + 8);        \
    kt0 = *(const bf16x8*)(gp + 2048);   kt1 = *(const bf16x8*)(gp + 2048 + 8); \
    wv0 = *(const bf16x8*)(Wbuf + tb);   wv1 = *(const bf16x8*)(Wbuf + tb + 8); \
    sl0 = *(const bf16x8*)(SLbuf + tb);  sl1 = *(const bf16x8*)(SLbuf + tb + 8);\
    if (tid < 128) uv = *(const bf16x8*)(Ubuf + ubb + (long)(CN) * 4096);       \
  } while (0)

#define WRITE_TILES(BUF) do {                                                   \
    char* bp_ = lds + (BUF) * 34816;                                            \
    *(bf16x8*)(bp_ + swz128(row, cg * 32)) = qv0;                               \
    *(bf16x8*)(bp_ + swz128(row, cg * 32 + 16)) = qv1;                          \
    *(bf16x8*)(bp_ + 8192 + swz128(row, cg * 32)) = wv0;                        \
    *(bf16x8*)(bp_ + 8192 + swz128(row, cg * 32 + 16)) = wv1;                   \
    *(bf16x8*)(bp_ + 16384 + swz128(row, cg * 32)) = sl0;                       \
    *(bf16x8*)(bp_ + 16384 + swz128(row, cg * 32 + 16)) = sl1;                  \
    *(bf16x8*)(bp_ + 24576 + swz128(row, cg * 32)) = kt0;                       \
    *(bf16x8*)(bp_ + 24576 + swz128(row, cg * 32 + 16)) = kt1;                  \
    if (tid < 128) *(bf16x8*)(bp_ + 32768 + ((tid >> 1) * 16 + (tid & 1) * 8) * 2) = uv; \
  } while (0)

  f32x4 sacc;
#pragma unroll
  for (int r = 0; r < 4; ++r)
    sacc[r] = state_in[(long)bh * 4096 + (dq * 16 + crow + r) * 64 + 16 * wid + rfrag];
#pragma unroll
  for (int r = 0; r < 4; ++r)
    *(unsigned short*)(ssb + swz128(crow + r, 2 * (16 * wid + rfrag))) = f2bf(sacc[r]);

  // prologue: stage chunk 0 into buf0; prefetch chunk 1 regs
  LOADREGS(0);
  WRITE_TILES(0);
  LOADREGS(1);
  LDS_BARRIER();

  for (int c = 0; c < NC_; ++c) {
    const int cur = c & 1;
    const char* bp = lds + cur * 34816;
    const int ta = 16 * wid + rfrag;

    // ---- stage A: P = W*S^T, Yq = Q*S^T; G = U - P -> sGT ----
    f32x4 p = {};
    f32x4 yac = {};
#pragma unroll
    for (int ks = 0; ks < 2; ++ks) {
      bf16x8 afw = *(const bf16x8*)(bp + 8192 + swz128(ta, ks * 64 + koff * 2));
      bf16x8 afq = *(const bf16x8*)(bp + swz128(ta, ks * 64 + koff * 2));
      bf16x8 bS = *(const bf16x8*)(ssb + swz128(rfrag, ks * 64 + koff * 2));
      p = __builtin_amdgcn_mfma_f32_16x16x32_bf16(afw, bS, p, 0, 0, 0);
      yac = __builtin_amdgcn_mfma_f32_16x16x32_bf16(afq, bS, yac, 0, 0, 0);
    }
#pragma unroll
    for (int r = 0; r < 4; ++r) {
      int t = 16 * wid + crow + r;
      float gg = bf2f(*(const unsigned short*)(bp + 32768 + (t * 16 + rfrag) * 2)) - p[r];
      *(unsigned short*)(gt + swz128(rfrag, 2 * t)) = f2bf(gg);
    }
    LDS_BARRIER();   // #2: GT produced -> consumed

    // ---- stage B: Y += SL*G ; S += G^T*K ; stage c+1 tiles (overlapped) ----
#pragma unroll
    for (int ks = 0; ks < 2; ++ks) {
      bf16x8 aSL = *(const bf16x8*)(bp + 16384 + swz128(ta, ks * 64 + koff * 2));
      bf16x8 bGT = *(const bf16x8*)(gt + swz128(rfrag, ks * 64 + koff * 2));
      yac = __builtin_amdgcn_mfma_f32_16x16x32_bf16(aSL, bGT, yac, 0, 0, 0);
    }
#pragma unroll
    for (int ks = 0; ks < 2; ++ks) {
      bf16x8 aGT = *(const bf16x8*)(gt + swz128(rfrag, ks * 64 + koff * 2));
      bf16x8 bKT = *(const bf16x8*)(bp + 24576 + swz128(16 * wid + rfrag, ks * 64 + koff * 2));
      sacc = __builtin_amdgcn_mfma_f32_16x16x32_bf16(aGT, bKT, sacc, 0, 0, 0);
    }
#pragma unroll
    for (int r = 0; r < 4; ++r) {
      int t = 16 * wid + crow + r;
      ybuf[(long)(b * 2048 + c * 64 + t) * 1024 + h * 64 + dq * 16 + rfrag] = f2bf(yac[r]);
    }
    // new S -> sS (read at next chunk's stage A, after boundary barrier)
#pragma unroll
    for (int r = 0; r < 4; ++r)
      *(unsigned short*)(ssb + swz128(crow + r, 2 * (16 * wid + rfrag))) = f2bf(sacc[r]);
    // stage chunk c+1 tiles into the other buffer; prefetch chunk c+2
    if (c + 1 < NC_) {
      WRITE_TILES(cur ^ 1);
      int cn = c + 2; if (cn > NC_ - 1) cn = NC_ - 1;
      LOADREGS(cn);
    }
    LDS_BARRIER();   // boundary: tiles staged + sS ready; reads of buf[cur] done
  }

#pragma unroll
  for (int r = 0; r < 4; ++r)
    state_out[(long)bh * 4096 + (dq * 16 + crow + r) * 64 + 16 * wid + rfrag] = sacc[r];
#undef LOADREGS
#undef WRITE_TILES
}

// ---------------- launch ----------------
extern "C" void kernel_launch(void* const* d_in, const int* in_sizes, int n_in,
                              void* d_out, int out_size, void* d_ws, size_t ws_size,
                              hipStream_t stream) {
  (void)in_sizes; (void)n_in; (void)out_size; (void)ws_size;
  const float* x     = (const float*)d_in[0];
  const float* Wq    = (const float*)d_in[1];
  const float* Wk    = (const float*)d_in[2];
  const float* Wv    = (const float*)d_in[3];
  const float* Wproj = (const float*)d_in[4];
  const float* a_raw = (const float*)d_in[5];
  const float* b_raw = (const float*)d_in[6];
  const float* state = (const float*)d_in[7];

  char* ws = (char*)d_ws;
  unsigned short* xbf = (unsigned short*)ws;                    // 16MB; reused as y
  unsigned short* W3  = (unsigned short*)(ws + (16l << 20));    // 6MB [Wq;Wk;Wv]
  unsigned short* Wp  = (unsigned short*)(ws + (22l << 20));    // 2MB
  unsigned short* qkv = (unsigned short*)(ws + (24l << 20));    // 48MB
  unsigned short* Ub  = (unsigned short*)(ws + (72l << 20));    // 16MB
  unsigned short* Wb  = (unsigned short*)(ws + (88l << 20));    // 16MB
  unsigned short* SLb = (unsigned short*)(ws + (104l << 20));   // 16MB -> 120MB total
  float* out = (float*)d_out;
  float* state_out = out + (long)B_ * T_ * C_;

  cvt_all<<<dim3(12288), dim3(256), 0, stream>>>(x, Wq, Wk, Wv, Wproj, xbf, W3, Wp);

  // QKV projection: 768 blocks = 3 exact CU-rounds
  gemm128x256<1><<<dim3(3072 / 256, 8192 / 128), dim3(512), 0, stream>>>(xbf, W3, (void*)qkv, 3072);

  chunk_prep<<<dim3(2048), dim3(256), 0, stream>>>(qkv, a_raw, b_raw, Ub, Wb, SLb);
  chunk_scan<<<dim3(256), dim3(256), 0, stream>>>(qkv, Ub, Wb, SLb, state, xbf, state_out);

  // out projection: 256 blocks = 1 exact CU-round, f32 out
  gemm128x256<0><<<dim3(1024 / 256, 8192 / 128), dim3(512), 0, stream>>>(xbf, Wp, (void*)out, 1024);
}

// Round 16
// 174.115 us; speedup vs baseline: 1.1159x; 1.0040x over previous
//
#include <hip/hip_runtime.h>
#include <hip/hip_bf16.h>
#include <cstdint>

#define B_ 4
#define T_ 2048
#define C_ 1024
#define H_ 16
#define D_ 64
#define NC_ 32   // chunks
#define L_ 64    // chunk length

typedef __attribute__((ext_vector_type(8))) short bf16x8;
typedef __attribute__((ext_vector_type(4))) float f32x4;

static __device__ __forceinline__ unsigned short f2bf(float f) {
  unsigned u = __float_as_uint(f);
  u += 0x7fff + ((u >> 16) & 1);   // round-to-nearest-even
  return (unsigned short)(u >> 16);
}
static __device__ __forceinline__ float bf2f(unsigned short b) {
  return __uint_as_float(((unsigned)b) << 16);
}
// XOR swizzle for 128B-stride LDS rows (T2): keeps 16B alignment, <=2-way conflicts
static __device__ __forceinline__ int swz128(int row, int byte) {
  return row * 128 + (byte ^ ((row & 7) << 4));
}

// Barrier that does NOT drain vmcnt (T4): LDS edges fenced via lgkmcnt(0).
#define LDS_BARRIER() asm volatile("s_waitcnt lgkmcnt(0)\ns_barrier" ::: "memory")

// ---------------- f32 -> bf16 convert (x + 4 weights in ONE launch) ----------------
__global__ __launch_bounds__(256) void cvt_all(const float* __restrict__ x,
                                               const float* __restrict__ wq,
                                               const float* __restrict__ wk,
                                               const float* __restrict__ wv,
                                               const float* __restrict__ wp,
                                               unsigned short* __restrict__ xbf,
                                               unsigned short* __restrict__ W3,
                                               unsigned short* __restrict__ Wp) {
  const int bidx = blockIdx.x;
  const float* src;
  unsigned short* dst;
  long base;
  if (bidx < 8192) {
    src = x; dst = xbf; base = (long)bidx * 1024;
  } else {
    const int g = (bidx - 8192) >> 10;
    src = (g == 0) ? wq : (g == 1) ? wk : (g == 2) ? wv : wp;
    dst = (g < 3) ? (W3 + (long)g * 1048576) : Wp;
    base = (long)((bidx - 8192) & 1023) * 1024;
  }
  long i = base + threadIdx.x * 4;
  float4 v = *reinterpret_cast<const float4*>(src + i);
  ushort4 o;
  o.x = f2bf(v.x); o.y = f2bf(v.y); o.z = f2bf(v.z); o.w = f2bf(v.w);
  *reinterpret_cast<ushort4*>(dst + i) = o;
}

// ========== 128x256 bf16 GEMM, 3-region rotation, 1 phase/K-tile ==========
// BM=128, BN=256, BK=64, 16 K-tiles (K=1024). 512 thr / 8 waves (2m x 4n,
// 64x64 per wave). LDS 144KB = 3 x 48KB regions {A 16K | B 32K}; tile t in
// region t%3; tile t+2 staged in phase t; counted vmcnt(6) at phase end
// drains tile t+1's 6 loads. Per phase: 16 ds_read_b128 -> 32 MFMA
// (reuse 2.0) and only 2 barriers per K-tile (was 4).

#define STAGEH(GP, GR0, KT, LOFF) do {                                            \
    const unsigned short* _s = (GP) + ((GR0) + wid * 8 + lr8) * 1024L             \
                               + (long)(KT) * 64 + skb * 8;                       \
    char* _d = (char*)lds + (LOFF) + wid * 1024;                                  \
    __builtin_amdgcn_global_load_lds((const __attribute__((address_space(1))) void*)_s,      \
        (__attribute__((address_space(3))) void*)_d, 16, 0, 0);                   \
    __builtin_amdgcn_global_load_lds((const __attribute__((address_space(1))) void*)(_s + 64 * 1024L), \
        (__attribute__((address_space(3))) void*)(_d + 8192), 16, 0, 0);          \
  } while (0)

#define PHASE1(RG, STG) do {                                                      \
    bf16x8 av[4][2], bv[4][2];                                                    \
    {                                                                             \
      const char* ab = (const char*)lds + (RG) + arow;                            \
      const char* bb = (const char*)lds + (RG) + 16384 + brow;                    \
      _Pragma("unroll")                                                           \
      for (int j = 0; j < 4; ++j) {                                               \
        av[j][0] = *(const bf16x8*)(ab + j * 4096 + cb0);                         \
        av[j][1] = *(const bf16x8*)(ab + j * 4096 + cb1);                         \
      }                                                                           \
      _Pragma("unroll")                                                           \
      for (int n = 0; n < 4; ++n) {                                               \
        bv[n][0] = *(const bf16x8*)(bb + n * 8192 + cb0);                         \
        bv[n][1] = *(const bf16x8*)(bb + n * 8192 + cb1);                         \
      }                                                                           \
    }                                                                             \
    STG;                                                                          \
    __builtin_amdgcn_s_barrier();                                                 \
    asm volatile("s_waitcnt lgkmcnt(0)" ::: "memory");                            \
    __builtin_amdgcn_sched_barrier(0);                                            \
    __builtin_amdgcn_s_setprio(1);                                                \
    _Pragma("unroll")                                                             \
    for (int j = 0; j < 4; ++j)                                                   \
      _Pragma("unroll")                                                           \
      for (int n = 0; n < 4; ++n)                                                 \
        acc[j][n] = __builtin_amdgcn_mfma_f32_16x16x32_bf16(                      \
            av[j][0], bv[n][0], acc[j][n], 0, 0, 0);                              \
    _Pragma("unroll")                                                             \
    for (int j = 0; j < 4; ++j)                                                   \
      _Pragma("unroll")                                                           \
      for (int n = 0; n < 4; ++n)                                                 \
        acc[j][n] = __builtin_amdgcn_mfma_f32_16x16x32_bf16(                      \
            av[j][1], bv[n][1], acc[j][n], 0, 0, 0);                              \
    __builtin_amdgcn_s_setprio(0);                                                \
    asm volatile("s_waitcnt vmcnt(6)" ::: "memory");                              \
    __builtin_amdgcn_s_barrier();                                                 \
  } while (0)

template<int OUT_BF16>
__global__ __launch_bounds__(512, 2) void gemm128x256(
    const unsigned short* __restrict__ A,
    const unsigned short* __restrict__ Bw,
    void* __restrict__ Cp, int N) {
  __shared__ __align__(16) char lds[147456];   // 3 x 48KB regions
  const int tid = threadIdx.x;
  const int wid = tid >> 6, lane = tid & 63;
  const int wm = wid >> 2, wn = wid & 3;
  const int f = lane & 15, g = lane >> 4;
  const int lr8 = lane >> 3, lc = lane & 7;
  const int skb = lc ^ lr8;                 // pre-swizzled source col-block
  // T1: bijective XCD-chunked swizzle (both grids % 8 == 0)
  const int bid = blockIdx.y * gridDim.x + blockIdx.x;
  const int cpx = (gridDim.x * gridDim.y) >> 3;
  const int sw = (bid & 7) * cpx + (bid >> 3);
  const long bM = (long)(sw / gridDim.x) * 128;
  const long bN = (long)(sw % gridDim.x) * 256;
  const int cb0 = ((0 + g) ^ (f & 7)) * 16;
  const int cb1 = ((4 + g) ^ (f & 7)) * 16;
  const int arow = (wm * 16 + f) * 128;     // A rows: wm*64? no: wm in {0,1} selects 64-row half via j*16 tiles
  const int brow = (wn * 16 + f) * 128;

  f32x4 acc[4][4] = {};

  // prologue: stage tile0 -> R0, tile1 -> R1; wait tile0 landed (counted)
  STAGEH(Bw, bN, 0, 16384);
  STAGEH(Bw, bN + 128, 0, 32768);
  STAGEH(A, bM, 0, 0);
  STAGEH(Bw, bN, 1, 49152 + 16384);
  STAGEH(Bw, bN + 128, 1, 49152 + 32768);
  STAGEH(A, bM, 1, 49152);
  asm volatile("s_waitcnt vmcnt(6)" ::: "memory");
  __builtin_amdgcn_s_barrier();

#pragma unroll
  for (int t = 0; t < 16; ++t) {
    const int rg = (t % 3) * 49152;
    const int ng = ((t + 2) % 3) * 49152;
    const int ts = (t + 2 > 15) ? 15 : t + 2;   // ghost clamp -> dead region
    PHASE1(rg,
           { STAGEH(Bw, bN, ts, ng + 16384); STAGEH(Bw, bN + 128, ts, ng + 32768); STAGEH(A, bM, ts, ng); });
  }
  asm volatile("s_waitcnt vmcnt(0)" ::: "memory");   // drain ghosts before exit

  // epilogue: wave (wm,wn); A row tiles j at wm*64 + j*16; B col tiles n at
  // quadrant layout (n>>1)*128 + (n&1)*64 + wn*16
#pragma unroll
  for (int mf = 0; mf < 4; ++mf) {
    long row = bM + mf * 32 + wm * 16 + g * 4;
#pragma unroll
    for (int nf = 0; nf < 4; ++nf) {
      long col = bN + (nf >> 1) * 128 + (nf & 1) * 64 + wn * 16 + f;
#pragma unroll
      for (int r = 0; r < 4; ++r) {
        if (OUT_BF16)
          ((unsigned short*)Cp)[(row + r) * (long)N + col] = f2bf(acc[mf][nf][r]);
        else
          ((float*)Cp)[(row + r) * (long)N + col] = acc[mf][nf][r];
      }
    }
  }
}

// ---------------- phase 1: per (bh, chunk) WY precompute ----------------
// Packs KT = K_norm^T into the dead V-slot of qkv (scan stages it vectorized).
__global__ __launch_bounds__(256) void chunk_prep(
    unsigned short* __restrict__ qkv,
    const float* __restrict__ a_raw, const float* __restrict__ b_raw,
    unsigned short* __restrict__ Ubuf, unsigned short* __restrict__ Wbuf,
    unsigned short* __restrict__ SLbuf) {
  __shared__ __align__(16) unsigned short sK[64 * 64];
  __shared__ __align__(16) unsigned short sQ[64 * 64];
  __shared__ __align__(16) unsigned short sV[64 * 64];
  __shared__ float sA[64 * 64];

  const int blk = blockIdx.x;           // bh*32 + c
  const int bh = blk >> 5, c = blk & 31;
  const int b = bh >> 4, h = bh & 15;
  const int tid = threadIdx.x;
  const int wid = tid >> 6, lane = tid & 63;

  const float alpha = 0.5f / (1.f + __expf(-a_raw[h]));
  const float beta  = 0.5f / (1.f + __expf(-b_raw[h]));

  {
    const int row = tid >> 2, cg = tid & 3;
    unsigned short* gp = qkv + (long)(b * 2048 + c * 64 + row) * 3072 + h * 64 + cg * 16;
    bf16x8 q0 = *(const bf16x8*)(gp);
    bf16x8 q1 = *(const bf16x8*)(gp + 8);
    bf16x8 k0 = *(const bf16x8*)(gp + 1024);
    bf16x8 k1 = *(const bf16x8*)(gp + 1024 + 8);
    bf16x8 v0 = *(const bf16x8*)(gp + 2048);
    bf16x8 v1 = *(const bf16x8*)(gp + 2048 + 8);
    float kf[16];
    float ss = 0.f;
#pragma unroll
    for (int i = 0; i < 8; ++i) { kf[i] = bf2f((unsigned short)k0[i]); ss += kf[i] * kf[i]; }
#pragma unroll
    for (int i = 0; i < 8; ++i) { kf[8 + i] = bf2f((unsigned short)k1[i]); ss += kf[8 + i] * kf[8 + i]; }
    ss += __shfl_xor(ss, 1);
    ss += __shfl_xor(ss, 2);
    const float inv = 1.f / fmaxf(sqrtf(ss), 1e-12f);
    bf16x8 n0, n1;
#pragma unroll
    for (int i = 0; i < 8; ++i) { n0[i] = (short)f2bf(kf[i] * inv); n1[i] = (short)f2bf(kf[8 + i] * inv); }
    *(bf16x8*)((char*)sK + swz128(row, cg * 32)) = n0;
    *(bf16x8*)((char*)sK + swz128(row, cg * 32 + 16)) = n1;
    *(bf16x8*)((char*)sQ + swz128(row, cg * 32)) = q0;
    *(bf16x8*)((char*)sQ + swz128(row, cg * 32 + 16)) = q1;
    *(bf16x8*)((char*)sV + row * 128 + cg * 32) = v0;
    *(bf16x8*)((char*)sV + row * 128 + cg * 32 + 16) = v1;
  }
  __syncthreads();

  // KT pack: slot[e][t] = K_norm[t][e] -> qkv V-slot (coalesced bf16x8 stores)
  {
    const int erow = tid >> 2, tq = tid & 3;
    unsigned short kt[16];
#pragma unroll
    for (int i = 0; i < 16; ++i)
      kt[i] = *(const unsigned short*)((const char*)sK + swz128(tq * 16 + i, 2 * erow));
    unsigned short* vp = qkv + (long)(b * 2048 + c * 64 + erow) * 3072 + 2048 + h * 64 + tq * 16;
    *(bf16x8*)vp = *(const bf16x8*)kt;
    *(bf16x8*)(vp + 8) = *(const bf16x8*)(kt + 8);
  }

  const int rfrag = lane & 15, koff = (lane >> 4) * 8, crow = (lane >> 4) * 4;
  const int w2 = wid & 1;
  if (wid < 2) {
#pragma unroll
    for (int mt = 0; mt < 2; ++mt) {
      const int m = w2 * 2 + mt;
      const int ra = 16 * m + rfrag;
      f32x4 acc[4] = {};
#pragma unroll
      for (int ks = 0; ks < 2; ++ks) {
        bf16x8 af = *(const bf16x8*)((const char*)sK + swz128(ra, ks * 64 + koff * 2));
#pragma unroll
        for (int n = 0; n < 4; ++n) {
          bf16x8 bf = *(const bf16x8*)((const char*)sK + swz128(16 * n + rfrag, ks * 64 + koff * 2));
          acc[n] = __builtin_amdgcn_mfma_f32_16x16x32_bf16(af, bf, acc[n], 0, 0, 0);
        }
      }
#pragma unroll
      for (int n = 0; n < 4; ++n)
#pragma unroll
        for (int r = 0; r < 4; ++r)
          sA[(16 * m + crow + r) * 64 + 16 * n + rfrag] = acc[n][r];
    }
  } else {
#pragma unroll
    for (int mt = 0; mt < 2; ++mt) {
      const int m = w2 * 2 + mt;
      const int ra = 16 * m + rfrag;
      f32x4 acc[4] = {};
#pragma unroll
      for (int ks = 0; ks < 2; ++ks) {
        bf16x8 af = *(const bf16x8*)((const char*)sQ + swz128(ra, ks * 64 + koff * 2));
#pragma unroll
        for (int n = 0; n < 4; ++n) {
          bf16x8 bf = *(const bf16x8*)((const char*)sK + swz128(16 * n + rfrag, ks * 64 + koff * 2));
          acc[n] = __builtin_amdgcn_mfma_f32_16x16x32_bf16(af, bf, acc[n], 0, 0, 0);
        }
      }
#pragma unroll
      for (int n = 0; n < 4; ++n)
#pragma unroll
        for (int r = 0; r < 4; ++r) {
          int t = 16 * m + crow + r, j = 16 * n + rfrag;
          SLbuf[(long)blk * 4096 + t * 64 + j] = (j < t) ? f2bf(acc[n][r]) : (unsigned short)0;
        }
    }
  }
  __syncthreads();

  if (wid < 2) {
    const int d = lane;
    float x[64];
#pragma unroll
    for (int t = 0; t < 64; ++t) {
      float rhs;
      if (wid == 0) rhs = beta * bf2f(sV[t * 64 + d]);
      else          rhs = alpha * bf2f(*(const unsigned short*)((const char*)sK + swz128(t, 2 * d)));
      float s = 0.f;
#pragma unroll
      for (int j = 0; j < t; ++j) s = fmaf(sA[t * 64 + j], x[j], s);
      x[t] = rhs - alpha * s;
    }
    unsigned short* ob = (wid == 0 ? Ubuf : Wbuf) + (long)blk * 4096 + d;
#pragma unroll
    for (int t = 0; t < 64; ++t) ob[t * 64] = f2bf(x[t]);
  }
}

// ---------------- phase 2: sequential chunk recurrence (R11 best version) ----------------
__global__ __launch_bounds__(256) void chunk_scan(
    const unsigned short* __restrict__ qkv,
    const unsigned short* __restrict__ Ubuf, const unsigned short* __restrict__ Wbuf,
    const unsigned short* __restrict__ SLbuf,
    const float* __restrict__ state_in, unsigned short* __restrict__ ybuf,
    float* __restrict__ state_out) {
  // layout (bytes): buf k at k*34816: Q+0, W+8192, SL+16384, KT+24576, U+32768(2KB)
  // sGT at 69632 (2KB), sS at 71680 (2KB) -> 72KB total
  __shared__ __align__(16) char lds[73728];

  const int bid0 = blockIdx.x;
  const int blk = (bid0 & 7) * 32 + (bid0 >> 3);   // T1 (256 % 8 == 0)
  const int bh = blk >> 2, dq = blk & 3;
  const int b = bh >> 4, h = bh & 15;
  const int tid = threadIdx.x, wid = tid >> 6, lane = tid & 63;
  const int rfrag = lane & 15, koff = (lane >> 4) * 8, crow = (lane >> 4) * 4;
  const int row = tid >> 2, cg = tid & 3;

  char* gt = lds + 69632;
  char* ssb = lds + 71680;

  const unsigned short* gpb = qkv + (long)(b * 2048 + row) * 3072 + h * 64 + cg * 16;
  const long tbb = ((long)(bh * 32) * 64 + row) * 64 + cg * 16;
  const long ubb = ((long)(bh * 32) * 64 + (tid >> 1)) * 64 + dq * 16 + (tid & 1) * 8;

  bf16x8 qv0, qv1, kt0, kt1, wv0, wv1, sl0, sl1, uv;
#define LOADREGS(CN) do {                                                       \
    const unsigned short* gp = gpb + (long)(CN) * 64 * 3072;                    \
    const long tb = tbb + (long)(CN) * 4096;                                    \
    qv0 = *(const bf16x8*)gp;            qv1 = *(const bf16x8*)(gp + 8);        \
    kt0 = *(const bf16x8*)(gp + 2048);   kt1 = *(const bf16x8*)(gp + 2048 + 8); \
    wv0 = *(const bf16x8*)(Wbuf + tb);   wv1 = *(const bf16x8*)(Wbuf + tb + 8); \
    sl0 = *(const bf16x8*)(SLbuf + tb);  sl1 = *(const bf16x8*)(SLbuf + tb + 8);\
    if (tid < 128) uv = *(const bf16x8*)(Ubuf + ubb + (long)(CN) * 4096);       \
  } while (0)

#define WRITE_TILES(BUF) do {                                                   \
    char* bp_ = lds + (BUF) * 34816;                                            \
    *(bf16x8*)(bp_ + swz128(row, cg * 32)) = qv0;                               \
    *(bf16x8*)(bp_ + swz128(row, cg * 32 + 16)) = qv1;                          \
    *(bf16x8*)(bp_ + 8192 + swz128(row, cg * 32)) = wv0;                        \
    *(bf16x8*)(bp_ + 8192 + swz128(row, cg * 32 + 16)) = wv1;                   \
    *(bf16x8*)(bp_ + 16384 + swz128(row, cg * 32)) = sl0;                       \
    *(bf16x8*)(bp_ + 16384 + swz128(row, cg * 32 + 16)) = sl1;                  \
    *(bf16x8*)(bp_ + 24576 + swz128(row, cg * 32)) = kt0;                       \
    *(bf16x8*)(bp_ + 24576 + swz128(row, cg * 32 + 16)) = kt1;                  \
    if (tid < 128) *(bf16x8*)(bp_ + 32768 + ((tid >> 1) * 16 + (tid & 1) * 8) * 2) = uv; \
  } while (0)

  f32x4 sacc;
#pragma unroll
  for (int r = 0; r < 4; ++r)
    sacc[r] = state_in[(long)bh * 4096 + (dq * 16 + crow + r) * 64 + 16 * wid + rfrag];
#pragma unroll
  for (int r = 0; r < 4; ++r)
    *(unsigned short*)(ssb + swz128(crow + r, 2 * (16 * wid + rfrag))) = f2bf(sacc[r]);

  // prologue: stage chunk 0 into buf0; prefetch chunk 1 regs
  LOADREGS(0);
  WRITE_TILES(0);
  LOADREGS(1);
  LDS_BARRIER();

  for (int c = 0; c < NC_; ++c) {
    const int cur = c & 1;
    const char* bp = lds + cur * 34816;
    const int ta = 16 * wid + rfrag;

    // ---- stage A: P = W*S^T, Yq = Q*S^T; G = U - P -> sGT ----
    f32x4 p = {};
    f32x4 yac = {};
#pragma unroll
    for (int ks = 0; ks < 2; ++ks) {
      bf16x8 afw = *(const bf16x8*)(bp + 8192 + swz128(ta, ks * 64 + koff * 2));
      bf16x8 afq = *(const bf16x8*)(bp + swz128(ta, ks * 64 + koff * 2));
      bf16x8 bS = *(const bf16x8*)(ssb + swz128(rfrag, ks * 64 + koff * 2));
      p = __builtin_amdgcn_mfma_f32_16x16x32_bf16(afw, bS, p, 0, 0, 0);
      yac = __builtin_amdgcn_mfma_f32_16x16x32_bf16(afq, bS, yac, 0, 0, 0);
    }
#pragma unroll
    for (int r = 0; r < 4; ++r) {
      int t = 16 * wid + crow + r;
      float gg = bf2f(*(const unsigned short*)(bp + 32768 + (t * 16 + rfrag) * 2)) - p[r];
      *(unsigned short*)(gt + swz128(rfrag, 2 * t)) = f2bf(gg);
    }
    LDS_BARRIER();   // #2: GT produced -> consumed

    // ---- stage B: Y += SL*G ; S += G^T*K ; stage c+1 tiles (overlapped) ----
#pragma unroll
    for (int ks = 0; ks < 2; ++ks) {
      bf16x8 aSL = *(const bf16x8*)(bp + 16384 + swz128(ta, ks * 64 + koff * 2));
      bf16x8 bGT = *(const bf16x8*)(gt + swz128(rfrag, ks * 64 + koff * 2));
      yac = __builtin_amdgcn_mfma_f32_16x16x32_bf16(aSL, bGT, yac, 0, 0, 0);
    }
#pragma unroll
    for (int ks = 0; ks < 2; ++ks) {
      bf16x8 aGT = *(const bf16x8*)(gt + swz128(rfrag, ks * 64 + koff * 2));
      bf16x8 bKT = *(const bf16x8*)(bp + 24576 + swz128(16 * wid + rfrag, ks * 64 + koff * 2));
      sacc = __builtin_amdgcn_mfma_f32_16x16x32_bf16(aGT, bKT, sacc, 0, 0, 0);
    }
#pragma unroll
    for (int r = 0; r < 4; ++r) {
      int t = 16 * wid + crow + r;
      ybuf[(long)(b * 2048 + c * 64 + t) * 1024 + h * 64 + dq * 16 + rfrag] = f2bf(yac[r]);
    }
    // new S -> sS (read at next chunk's stage A, after boundary barrier)
#pragma unroll
    for (int r = 0; r < 4; ++r)
      *(unsigned short*)(ssb + swz128(crow + r, 2 * (16 * wid + rfrag))) = f2bf(sacc[r]);
    // stage chunk c+1 tiles into the other buffer; prefetch chunk c+2
    if (c + 1 < NC_) {
      WRITE_TILES(cur ^ 1);
      int cn = c + 2; if (cn > NC_ - 1) cn = NC_ - 1;
      LOADREGS(cn);
    }
    LDS_BARRIER();   // boundary: tiles staged + sS ready; reads of buf[cur] done
  }

#pragma unroll
  for (int r = 0; r < 4; ++r)
    state_out[(long)bh * 4096 + (dq * 16 + crow + r) * 64 + 16 * wid + rfrag] = sacc[r];
#undef LOADREGS
#undef WRITE_TILES
}

// ---------------- launch ----------------
extern "C" void kernel_launch(void* const* d_in, const int* in_sizes, int n_in,
                              void* d_out, int out_size, void* d_ws, size_t ws_size,
                              hipStream_t stream) {
  (void)in_sizes; (void)n_in; (void)out_size; (void)ws_size;
  const float* x     = (const float*)d_in[0];
  const float* Wq    = (const float*)d_in[1];
  const float* Wk    = (const float*)d_in[2];
  const float* Wv    = (const float*)d_in[3];
  const float* Wproj = (const float*)d_in[4];
  const float* a_raw = (const float*)d_in[5];
  const float* b_raw = (const float*)d_in[6];
  const float* state = (const float*)d_in[7];

  char* ws = (char*)d_ws;
  unsigned short* xbf = (unsigned short*)ws;                    // 16MB; reused as y
  unsigned short* W3  = (unsigned short*)(ws + (16l << 20));    // 6MB [Wq;Wk;Wv]
  unsigned short* Wp  = (unsigned short*)(ws + (22l << 20));    // 2MB
  unsigned short* qkv = (unsigned short*)(ws + (24l << 20));    // 48MB
  unsigned short* Ub  = (unsigned short*)(ws + (72l << 20));    // 16MB
  unsigned short* Wb  = (unsigned short*)(ws + (88l << 20));    // 16MB
  unsigned short* SLb = (unsigned short*)(ws + (104l << 20));   // 16MB -> 120MB total
  float* out = (float*)d_out;
  float* state_out = out + (long)B_ * T_ * C_;

  cvt_all<<<dim3(12288), dim3(256), 0, stream>>>(x, Wq, Wk, Wv, Wproj, xbf, W3, Wp);

  // QKV projection: 768 blocks = 3 exact CU-rounds
  gemm128x256<1><<<dim3(3072 / 256, 8192 / 128), dim3(512), 0, stream>>>(xbf, W3, (void*)qkv, 3072);

  chunk_prep<<<dim3(2048), dim3(256), 0, stream>>>(qkv, a_raw, b_raw, Ub, Wb, SLb);
  chunk_scan<<<dim3(256), dim3(256), 0, stream>>>(qkv, Ub, Wb, SLb, state, xbf, state_out);

  // out projection: 256 blocks = 1 exact CU-round, f32 out
  gemm128x256<0><<<dim3(1024 / 256, 8192 / 128), dim3(512), 0, stream>>>(xbf, Wp, (void*)out, 1024);
}